// Round 8
// baseline (1322.306 us; speedup 1.0000x reference)
//
#include <hip/hip_runtime.h>

#define N_ATOMS 100000
#define N_EDGES 3200000
#define N_RBF 8
#define HIDDEN 16

#define NB 4096
#define TSCALE 64.0f   // bins per unit r2; table covers r2 in [0, 64)

// d_out layout (floats):
#define OFF_TE   0
#define OFF_NE   1
#define OFF_F    (1 + N_ATOMS)
#define OFF_VIR  (1 + N_ATOMS + 3*N_ATOMS)
#define OFF_AV   (OFF_VIR + 9)

#define WPAD (N_ATOMS + 4)
#define NBLK16 (N_ATOMS / 16)                   // 6250 blocks in fused16
#define AVBLK ((N_ATOMS + 255) / 256)           // 391 blocks in av_finalize
#define SCAN_B 1024
#define SCAN_NB ((N_ATOMS + SCAN_B) / SCAN_B)   // 98 blocks cover N_ATOMS+1

// ---- new-path ws layout (words) ----
#define NTAB_S   0
#define NTAB_G   (NB*HIDDEN)
#define NOFF_R   (2*NB*HIDDEN)
#define NCNT_R8  (NOFF_R + WPAD)             // 8 per-XCD histogram copies (recv)
#define NTEP     (NCNT_R8 + 8*WPAD)
#define NVPART   (NTEP + 8192)
#define NAV6S    (NVPART + 4096)             // 8 per-XCD virial accumulators (2.4MB each)
#define NPAY_R   (NAV6S + 48*N_ATOMS)
#define NBSUM    NPAY_R                      // scan temp aliases pay_r (dead before scatter)
#define NEND     (NPAY_R + 4*N_EDGES)        // 18,643,396 words = 74.6 MB

// ---- fallback (round-3) ws layout ----
#define WOFF_OFFS_R 0
#define WOFF_OFFS_S WPAD
#define WOFF_RANK_R (2*WPAD)
#define WOFF_RANK_S (WOFF_RANK_R + N_EDGES)
#define WOFF_EID_R  (WOFF_RANK_S + N_EDGES)
#define WOFF_EID_S  (WOFF_EID_R + N_EDGES)
#define WOFF_DR2    (WOFF_EID_S + N_EDGES)
#define WOFF_AV6    (WOFF_DR2 + N_EDGES)
#define WOFF_END    (WOFF_AV6 + 6*N_ATOMS)

__device__ inline unsigned int get_xcd() {
    unsigned int xcd;
    asm volatile("s_getreg_b32 %0, hwreg(HW_REG_XCC_ID)" : "=s"(xcd));
    return xcd & 7;
}

__device__ inline void l2_atomic_addf(float* p, float v) {
    __hip_atomic_fetch_add(p, v, __ATOMIC_RELAXED, __HIP_MEMORY_SCOPE_WORKGROUP);
}

// ---------------- table build ----------------
__global__ void build_tables(const float* __restrict__ W1, const float* __restrict__ b1,
                             const float* __restrict__ alphas,
                             float* __restrict__ s_tab, float* __restrict__ g_tab) {
    int idx = blockIdx.x * blockDim.x + threadIdx.x;   // NB*HIDDEN = 65536
    int b = idx >> 4, j = idx & 15;
    float r2 = (float)b / TSCALE;
    float pre = b1[j], pw = 0.f;
    #pragma unroll
    for (int f = 0; f < N_RBF; ++f) {
        float al = alphas[f];
        float ph = __expf(-r2 * al);
        float w  = W1[f*HIDDEN + j];
        pre += ph * w;
        pw  += al * ph * w;
    }
    float sig = 1.f / (1.f + __expf(-pre));
    s_tab[idx] = pre * sig;
    g_tab[idx] = sig * (1.f + pre * (1.f - sig)) * pw;
}

// ---------------- CSR build (recv only): per-XCD histogram, L2-local ----------------

__global__ void count8_r(const int* __restrict__ ei, int* __restrict__ cnt_r8) {
    unsigned int xcd = get_xcd();
    int e = blockIdx.x * blockDim.x + threadIdx.x;
    if (e >= N_EDGES) return;
    int recv = ei[N_EDGES + e];
    __hip_atomic_fetch_add(&cnt_r8[xcd * WPAD + recv], 1,
                           __ATOMIC_RELAXED, __HIP_MEMORY_SCOPE_WORKGROUP);
}

__global__ void xcd_prefix_r(int* __restrict__ cnt_r8, int* __restrict__ offs_r) {
    int a = blockIdx.x * blockDim.x + threadIdx.x;
    if (a >= N_ATOMS) return;
    int t = 0;
    #pragma unroll
    for (int x = 0; x < 8; ++x) {
        int c = cnt_r8[x*WPAD + a];
        cnt_r8[x*WPAD + a] = t;
        t += c;
    }
    offs_r[a] = t;
}

// ---------------- parallel 3-phase exclusive scan over N_ATOMS+1 ----------------

__global__ void scanA(int* __restrict__ a, int* __restrict__ bsum) {
    const int n = N_ATOMS + 1;
    int i = blockIdx.x * SCAN_B + threadIdx.x;
    int v = (i < n) ? a[i] : 0;
    int lane = threadIdx.x & 63, w = threadIdx.x >> 6;
    int s = v;
    #pragma unroll
    for (int o = 1; o < 64; o <<= 1) {
        int t = __shfl_up(s, o);
        if (lane >= o) s += t;
    }
    __shared__ int wsum[16];
    if (lane == 63) wsum[w] = s;
    __syncthreads();
    if (threadIdx.x < 16) {
        int sc = wsum[threadIdx.x];
        #pragma unroll
        for (int o = 1; o < 16; o <<= 1) {
            int t = __shfl_up(sc, o);
            if ((int)threadIdx.x >= o) sc += t;
        }
        wsum[threadIdx.x] = sc;
    }
    __syncthreads();
    int wpre = (w > 0) ? wsum[w-1] : 0;
    if (i < n) a[i] = s - v + wpre;
    if (threadIdx.x == 0) bsum[blockIdx.x] = wsum[15];
}

__global__ void scanB(int* __restrict__ bsum) {
    __shared__ int lds[SCAN_NB];
    if (threadIdx.x < SCAN_NB) lds[threadIdx.x] = bsum[threadIdx.x];
    __syncthreads();
    if (threadIdx.x == 0) {
        int run = 0;
        for (int i = 0; i < SCAN_NB; ++i) { int t = lds[i]; lds[i] = run; run += t; }
    }
    __syncthreads();
    if (threadIdx.x < SCAN_NB) bsum[threadIdx.x] = lds[threadIdx.x];
}

__global__ void scanC(int* __restrict__ a, const int* __restrict__ bsum) {
    int i = blockIdx.x * SCAN_B + threadIdx.x;
    if (i < N_ATOMS + 1) a[i] += bsum[blockIdx.x];
}

// ---------------- scatter (recv only): allocator-style ----------------
// pay_r[rs] = (vx,vy,vz, bitcast(send_atom))
__global__ void scatter_r(const int* __restrict__ ei,
                          const int* __restrict__ offs_r, int* __restrict__ cnt_r8,
                          const float* __restrict__ vectors,
                          float4* __restrict__ pay_r) {
    unsigned int xcd = get_xcd();
    int e = blockIdx.x * blockDim.x + threadIdx.x;
    if (e >= N_EDGES) return;
    int send = ei[e], recv = ei[N_EDGES + e];
    int br = __hip_atomic_fetch_add(&cnt_r8[xcd*WPAD + recv], 1,
                                    __ATOMIC_RELAXED, __HIP_MEMORY_SCOPE_WORKGROUP);
    int rs = offs_r[recv] + br;
    float vx = vectors[3*e], vy = vectors[3*e+1], vz = vectors[3*e+2];
    pay_r[rs] = make_float4(vx, vy, vz, __int_as_float(send));
}

// ---------------- fused: fwd + node MLP + bwd; send virial via L2-local atomics ----

__global__ void fused16(const float4* __restrict__ pay_r,
                        const float* __restrict__ positions,
                        const float* __restrict__ lg,
                        const float* __restrict__ W2, const float* __restrict__ w3,
                        const float* __restrict__ field,
                        const int* __restrict__ offs_r,
                        const float* __restrict__ s_tab, const float* __restrict__ g_tab,
                        float* __restrict__ av6s,
                        float* __restrict__ tepart, float* __restrict__ out) {
    unsigned int xcd = get_xcd();
    float* avx = av6s + (size_t)xcd * 6 * N_ATOMS;
    int tid = blockIdx.x * blockDim.x + threadIdx.x;
    int a = tid >> 4;
    int sl = threadIdx.x & 15;
    int lane = threadIdx.x & 63;
    int gb = lane & 48;
    int start = offs_r[a], end = offs_r[a + 1];
    int k0 = start + sl;

    float m[HIDDEN];
    #pragma unroll
    for (int j = 0; j < HIDDEN; ++j) m[j] = 0.f;

    // ---- pass 1: forward via S-table ----
    for (int k = k0; k < end; k += 16) {
        float4 p = pay_r[k];
        float r2 = p.x*p.x + p.y*p.y + p.z*p.z;
        float x = fminf(r2 * TSCALE, (float)(NB - 2) + 0.999f);
        int i = (int)x;
        float f = x - (float)i;
        const float4* r0 = (const float4*)(s_tab + i * HIDDEN);
        const float4* r1 = (const float4*)(s_tab + (i + 1) * HIDDEN);
        #pragma unroll
        for (int q = 0; q < 4; ++q) {
            float4 A = r0[q], B = r1[q];
            m[4*q+0] += A.x + f * (B.x - A.x);
            m[4*q+1] += A.y + f * (B.y - A.y);
            m[4*q+2] += A.z + f * (B.z - A.z);
            m[4*q+3] += A.w + f * (B.w - A.w);
        }
    }

    #pragma unroll
    for (int o = 1; o < 16; o <<= 1) {
        #pragma unroll
        for (int j = 0; j < HIDDEN; ++j) m[j] += __shfl_xor(m[j], o);
    }

    // ---- node MLP, channel j = sl per lane ----
    float aj = 0.f;
    #pragma unroll
    for (int i = 0; i < HIDDEN; ++i) aj += m[i] * W2[i*HIDDEN + sl];
    float sigj = 1.f / (1.f + __expf(-aj));
    float l = lg[a];
    float w3j = w3[sl];
    float sd = aj * sigj * w3j;
    #pragma unroll
    for (int o = 1; o < 16; o <<= 1) sd += __shfl_xor(sd, o);
    float dAj = l * w3j * sigj * (1.f + aj * (1.f - sigj));
    float gown = 0.f;
    #pragma unroll
    for (int q = 0; q < HIDDEN; ++q) {
        float dq = __shfl(dAj, gb | q);
        gown += dq * W2[sl*HIDDEN + q];
    }
    float g[HIDDEN];
    #pragma unroll
    for (int q = 0; q < HIDDEN; ++q) g[q] = __shfl(gown, gb | q);

    float contrib = 0.f;
    if (sl == 0) {
        float ne = sd + positions[3*a]*field[0] + positions[3*a+1]*field[1]
                      + positions[3*a+2]*field[2];
        out[OFF_NE + a] = ne;
        out[OFF_F + 3*a + 0] = -l * field[0];
        out[OFF_F + 3*a + 1] = -l * field[1];
        out[OFF_F + 3*a + 2] = -l * field[2];
        contrib = ne * l;
    }

    // ---- pass 2: backward via G-table; send virial scattered L2-locally ----
    float axx=0.f, axy=0.f, axz=0.f, ayy=0.f, ayz=0.f, azz=0.f;
    for (int k = k0; k < end; k += 16) {
        float4 p = pay_r[k];
        float r2 = p.x*p.x + p.y*p.y + p.z*p.z;
        float x = fminf(r2 * TSCALE, (float)(NB - 2) + 0.999f);
        int i = (int)x;
        float f = x - (float)i;
        const float4* r0 = (const float4*)(g_tab + i * HIDDEN);
        const float4* r1 = (const float4*)(g_tab + (i + 1) * HIDDEN);
        float dr2 = 0.f;
        #pragma unroll
        for (int q = 0; q < 4; ++q) {
            float4 A = r0[q], B = r1[q];
            dr2 -= g[4*q+0] * (A.x + f * (B.x - A.x));
            dr2 -= g[4*q+1] * (A.y + f * (B.y - A.y));
            dr2 -= g[4*q+2] * (A.z + f * (B.z - A.z));
            dr2 -= g[4*q+3] * (A.w + f * (B.w - A.w));
        }
        float txx = dr2*p.x*p.x, txy = dr2*p.x*p.y, txz = dr2*p.x*p.z;
        float tyy = dr2*p.y*p.y, tyz = dr2*p.y*p.z, tzz = dr2*p.z*p.z;
        // send-side deposit: 6 L2-local atomics into this XCD's 2.4MB replica
        int sa = __float_as_int(p.w);
        float* b = avx + (size_t)sa * 6;
        l2_atomic_addf(b+0, txx); l2_atomic_addf(b+1, txy); l2_atomic_addf(b+2, txz);
        l2_atomic_addf(b+3, tyy); l2_atomic_addf(b+4, tyz); l2_atomic_addf(b+5, tzz);
        axx += txx; axy += txy; axz += txz;
        ayy += tyy; ayz += tyz; azz += tzz;
    }
    #pragma unroll
    for (int o = 1; o < 16; o <<= 1) {
        axx += __shfl_xor(axx, o); axy += __shfl_xor(axy, o); axz += __shfl_xor(axz, o);
        ayy += __shfl_xor(ayy, o); ayz += __shfl_xor(ayz, o); azz += __shfl_xor(azz, o);
    }
    if (sl == 0) {
        // recv-side deposit (atom owned by this block, but send atomics may collide)
        float* b = avx + (size_t)a * 6;
        l2_atomic_addf(b+0, axx); l2_atomic_addf(b+1, axy); l2_atomic_addf(b+2, axz);
        l2_atomic_addf(b+3, ayy); l2_atomic_addf(b+4, ayz); l2_atomic_addf(b+5, azz);
    }

    // total-energy block partial (no global atomic)
    __shared__ float red[4];
    if (sl != 0) contrib = 0.f;
    contrib += __shfl_xor(contrib, 16);
    contrib += __shfl_xor(contrib, 32);
    int w = threadIdx.x >> 6;
    if (lane == 0) red[w] = contrib;
    __syncthreads();
    if (threadIdx.x == 0) tepart[blockIdx.x] = red[0]+red[1]+red[2]+red[3];
}

// -------- per-atom: sum the 8 XCD replicas -> atom_virial; block virial partials ----

__global__ void av_finalize(const float* __restrict__ av6s,
                            float* __restrict__ vpart, float* __restrict__ out) {
    int a = blockIdx.x * blockDim.x + threadIdx.x;
    float s0=0.f,s1=0.f,s2=0.f,s3=0.f,s4=0.f,s5=0.f;
    if (a < N_ATOMS) {
        #pragma unroll
        for (int x = 0; x < 8; ++x) {
            const float2* p = (const float2*)(av6s + (size_t)x*6*N_ATOMS + (size_t)a*6);
            float2 p0 = p[0], p1 = p[1], p2 = p[2];
            s0 += p0.x; s1 += p0.y; s2 += p1.x;
            s3 += p1.y; s4 += p2.x; s5 += p2.y;
        }
        float* o9 = out + OFF_AV + (size_t)a * 9;
        o9[0] = s0; o9[1] = s1; o9[2] = s2;
        o9[3] = s1; o9[4] = s3; o9[5] = s4;
        o9[6] = s2; o9[7] = s4; o9[8] = s5;
    }
    // block reduction of the 6 components for the global virial
    float acc[6] = {s0,s1,s2,s3,s4,s5};
    int lane = threadIdx.x & 63, w = threadIdx.x >> 6;
    #pragma unroll
    for (int c = 0; c < 6; ++c) {
        #pragma unroll
        for (int o = 1; o < 64; o <<= 1) acc[c] += __shfl_xor(acc[c], o);
    }
    __shared__ float sh[4][6];
    if (lane == 0) {
        #pragma unroll
        for (int c = 0; c < 6; ++c) sh[w][c] = acc[c];
    }
    __syncthreads();
    if (threadIdx.x < 6) {
        vpart[blockIdx.x * 6 + threadIdx.x] =
            sh[0][threadIdx.x] + sh[1][threadIdx.x] + sh[2][threadIdx.x] + sh[3][threadIdx.x];
    }
}

// -------- final reduce of TE + virial partials: one block, plain stores --------

__global__ void finalize_kernel(const float* __restrict__ tepart,
                                const float* __restrict__ vpart,
                                float* __restrict__ out) {
    int t = threadIdx.x;
    float acc[7];
    #pragma unroll
    for (int c = 0; c < 7; ++c) acc[c] = 0.f;
    for (int i = t; i < NBLK16; i += 1024) acc[0] += tepart[i];
    for (int i = t; i < AVBLK; i += 1024) {
        const float* p = vpart + (size_t)i * 6;
        acc[1] += p[0]; acc[2] += p[1]; acc[3] += p[2];
        acc[4] += p[3]; acc[5] += p[4]; acc[6] += p[5];
    }
    #pragma unroll
    for (int c = 0; c < 7; ++c) {
        #pragma unroll
        for (int o = 1; o < 64; o <<= 1) acc[c] += __shfl_xor(acc[c], o);
    }
    __shared__ float sh[16][8];
    int lane = t & 63, w = t >> 6;
    if (lane == 0) {
        #pragma unroll
        for (int c = 0; c < 7; ++c) sh[w][c] = acc[c];
    }
    __syncthreads();
    if (t == 0) {
        float s[7];
        #pragma unroll
        for (int c = 0; c < 7; ++c) {
            float v = 0.f;
            #pragma unroll
            for (int q = 0; q < 16; ++q) v += sh[q][c];
            s[c] = v;
        }
        out[OFF_TE] = s[0];
        out[OFF_VIR + 0] = s[1]; out[OFF_VIR + 1] = s[2]; out[OFF_VIR + 2] = s[3];
        out[OFF_VIR + 3] = s[2]; out[OFF_VIR + 4] = s[4]; out[OFF_VIR + 5] = s[5];
        out[OFF_VIR + 6] = s[3]; out[OFF_VIR + 7] = s[5]; out[OFF_VIR + 8] = s[6];
    }
}

// ================= fallback (round-3 verified path) =================

__global__ void count_kernel(const int* __restrict__ ei,
                             int* __restrict__ cnt_r, int* __restrict__ cnt_s,
                             int* __restrict__ rank_r, int* __restrict__ rank_s) {
    int e = blockIdx.x * blockDim.x + threadIdx.x;
    if (e >= N_EDGES) return;
    int send = ei[e], recv = ei[N_EDGES + e];
    rank_r[e] = atomicAdd(&cnt_r[recv], 1);
    rank_s[e] = atomicAdd(&cnt_s[send], 1);
}

__global__ void scan_kernel(int* __restrict__ offs_r, int* __restrict__ offs_s) {
    int* a = (blockIdx.x == 0) ? offs_r : offs_s;
    const int n = N_ATOMS + 1;
    __shared__ int wsum[4];
    __shared__ int carry_s;
    if (threadIdx.x == 0) carry_s = 0;
    __syncthreads();
    int lane = threadIdx.x & 63, w = threadIdx.x >> 6;
    for (int base = 0; base < n; base += 256) {
        int i = base + threadIdx.x;
        int v = (i < n) ? a[i] : 0;
        int s = v;
        #pragma unroll
        for (int o = 1; o < 64; o <<= 1) {
            int t = __shfl_up(s, o);
            if (lane >= o) s += t;
        }
        if (lane == 63) wsum[w] = s;
        __syncthreads();
        int wpre = 0;
        for (int k = 0; k < w; ++k) wpre += wsum[k];
        int incl = s + wpre;
        int total = wsum[0] + wsum[1] + wsum[2] + wsum[3];
        int excl = incl - v + carry_s;
        if (i < n) a[i] = excl;
        __syncthreads();
        if (threadIdx.x == 0) carry_s += total;
        __syncthreads();
    }
}

__global__ void scatter_kernel(const int* __restrict__ ei,
                               const int* __restrict__ offs_r, const int* __restrict__ offs_s,
                               const int* __restrict__ rank_r, const int* __restrict__ rank_s,
                               int* __restrict__ eid_r, int* __restrict__ eid_s) {
    int e = blockIdx.x * blockDim.x + threadIdx.x;
    if (e >= N_EDGES) return;
    int send = ei[e], recv = ei[N_EDGES + e];
    eid_r[offs_r[recv] + rank_r[e]] = e;
    eid_s[offs_s[send] + rank_s[e]] = e;
}

__global__ void fused_kernel(const float* __restrict__ vectors,
                             const float* __restrict__ positions,
                             const float* __restrict__ lg,
                             const float* __restrict__ W1, const float* __restrict__ b1,
                             const float* __restrict__ W2, const float* __restrict__ w3,
                             const float* __restrict__ field, const float* __restrict__ alphas,
                             const int* __restrict__ offs_r, const int* __restrict__ eid_r,
                             float* __restrict__ dr2buf, float* __restrict__ av6,
                             float* __restrict__ out) {
    int a = (blockIdx.x * blockDim.x + threadIdx.x) >> 6;
    int lane = threadIdx.x & 63;
    int start = offs_r[a], end = offs_r[a + 1];
    float al[N_RBF];
    #pragma unroll
    for (int f = 0; f < N_RBF; ++f) al[f] = alphas[f];
    float m[HIDDEN];
    #pragma unroll
    for (int j = 0; j < HIDDEN; ++j) m[j] = 0.f;
    float t[HIDDEN], paw[HIDDEN];
    float vx0 = 0.f, vy0 = 0.f, vz0 = 0.f;
    int e0 = -1;
    int k0 = start + lane;
    for (int k = k0; k < end; k += 64) {
        int e = eid_r[k];
        float vx = vectors[3*e], vy = vectors[3*e+1], vz = vectors[3*e+2];
        float r2 = vx*vx + vy*vy + vz*vz;
        float phi[N_RBF], apf[N_RBF];
        #pragma unroll
        for (int f = 0; f < N_RBF; ++f) { phi[f] = __expf(-r2 * al[f]); apf[f] = al[f] * phi[f]; }
        bool first = (k == k0);
        if (first) { e0 = e; vx0 = vx; vy0 = vy; vz0 = vz; }
        #pragma unroll
        for (int j = 0; j < HIDDEN; ++j) {
            float pre = b1[j];
            float pw = 0.f;
            #pragma unroll
            for (int f = 0; f < N_RBF; ++f) {
                float w = W1[f*HIDDEN + j];
                pre += phi[f] * w;
                pw  += apf[f] * w;
            }
            float sig = 1.f / (1.f + __expf(-pre));
            m[j] += pre * sig;
            if (first) { t[j] = sig * (1.f + pre * (1.f - sig)); paw[j] = pw; }
        }
    }
    #pragma unroll
    for (int o = 1; o < 64; o <<= 1) {
        #pragma unroll
        for (int j = 0; j < HIDDEN; ++j) m[j] += __shfl_xor(m[j], o);
    }
    int jj = lane & 15;
    int gbase = lane & 48;
    float aj = 0.f;
    #pragma unroll
    for (int i = 0; i < HIDDEN; ++i) aj += m[i] * W2[i*HIDDEN + jj];
    float sigj = 1.f / (1.f + __expf(-aj));
    float l = lg[a];
    float sd = aj * sigj * w3[jj];
    #pragma unroll
    for (int o = 1; o < 16; o <<= 1) sd += __shfl_xor(sd, o);
    float dAj = l * w3[jj] * sigj * (1.f + aj * (1.f - sigj));
    float dAv[HIDDEN];
    #pragma unroll
    for (int q = 0; q < HIDDEN; ++q) dAv[q] = __shfl(dAj, gbase | q);
    float gown = 0.f;
    #pragma unroll
    for (int j2 = 0; j2 < HIDDEN; ++j2) gown += dAv[j2] * W2[jj*HIDDEN + j2];
    float g[HIDDEN];
    #pragma unroll
    for (int q = 0; q < HIDDEN; ++q) g[q] = __shfl(gown, gbase | q);
    float contrib = 0.f;
    if (lane == 0) {
        float ne = sd + positions[3*a]*field[0] + positions[3*a+1]*field[1]
                      + positions[3*a+2]*field[2];
        out[OFF_NE + a] = ne;
        out[OFF_F + 3*a + 0] = -l * field[0];
        out[OFF_F + 3*a + 1] = -l * field[1];
        out[OFF_F + 3*a + 2] = -l * field[2];
        contrib = ne * l;
    }
    float axx=0.f, axy=0.f, axz=0.f, ayy=0.f, ayz=0.f, azz=0.f;
    if (k0 < end) {
        float dr2 = 0.f;
        #pragma unroll
        for (int j = 0; j < HIDDEN; ++j) dr2 -= (g[j] * t[j]) * paw[j];
        dr2buf[e0] = dr2;
        axx = dr2*vx0*vx0; axy = dr2*vx0*vy0; axz = dr2*vx0*vz0;
        ayy = dr2*vy0*vy0; ayz = dr2*vy0*vz0; azz = dr2*vz0*vz0;
    }
    for (int k = k0 + 64; k < end; k += 64) {
        int e = eid_r[k];
        float vx = vectors[3*e], vy = vectors[3*e+1], vz = vectors[3*e+2];
        float r2 = vx*vx + vy*vy + vz*vz;
        float phi[N_RBF], apf[N_RBF];
        #pragma unroll
        for (int f = 0; f < N_RBF; ++f) { phi[f] = __expf(-r2 * al[f]); apf[f] = al[f] * phi[f]; }
        float dr2 = 0.f;
        #pragma unroll
        for (int j = 0; j < HIDDEN; ++j) {
            float pre = b1[j];
            float pw = 0.f;
            #pragma unroll
            for (int f = 0; f < N_RBF; ++f) {
                float w = W1[f*HIDDEN + j];
                pre += phi[f] * w;
                pw  += apf[f] * w;
            }
            float sig = 1.f / (1.f + __expf(-pre));
            float tt = sig * (1.f + pre * (1.f - sig));
            dr2 -= (g[j] * tt) * pw;
        }
        dr2buf[e] = dr2;
        axx += dr2*vx*vx; axy += dr2*vx*vy; axz += dr2*vx*vz;
        ayy += dr2*vy*vy; ayz += dr2*vy*vz; azz += dr2*vz*vz;
    }
    #pragma unroll
    for (int o = 1; o < 64; o <<= 1) {
        axx += __shfl_xor(axx, o); axy += __shfl_xor(axy, o); axz += __shfl_xor(axz, o);
        ayy += __shfl_xor(ayy, o); ayz += __shfl_xor(ayz, o); azz += __shfl_xor(azz, o);
    }
    if (lane == 0) {
        float2* p = (float2*)(av6 + (size_t)a * 6);
        p[0] = make_float2(axx, axy);
        p[1] = make_float2(axz, ayy);
        p[2] = make_float2(ayz, azz);
    }
    __shared__ float red[4];
    int w = threadIdx.x >> 6;
    if (lane == 0) red[w] = contrib;
    __syncthreads();
    if (threadIdx.x == 0) atomicAdd(&out[OFF_TE], red[0]+red[1]+red[2]+red[3]);
}

__global__ void bwd_send_kernel(const float* __restrict__ vectors,
                                const int* __restrict__ offs_s, const int* __restrict__ eid_s,
                                const float* __restrict__ dr2buf, const float* __restrict__ av6,
                                float* __restrict__ out) {
    int a = (blockIdx.x * blockDim.x + threadIdx.x) >> 6;
    int lane = threadIdx.x & 63;
    int start = offs_s[a], end = offs_s[a + 1];
    float axx=0.f, axy=0.f, axz=0.f, ayy=0.f, ayz=0.f, azz=0.f;
    for (int k = start + lane; k < end; k += 64) {
        int e = eid_s[k];
        float dr2 = dr2buf[e];
        float vx = vectors[3*e], vy = vectors[3*e+1], vz = vectors[3*e+2];
        axx += dr2*vx*vx; axy += dr2*vx*vy; axz += dr2*vx*vz;
        ayy += dr2*vy*vy; ayz += dr2*vy*vz; azz += dr2*vz*vz;
    }
    #pragma unroll
    for (int o = 1; o < 64; o <<= 1) {
        axx += __shfl_xor(axx, o); axy += __shfl_xor(axy, o); axz += __shfl_xor(axz, o);
        ayy += __shfl_xor(ayy, o); ayz += __shfl_xor(ayz, o); azz += __shfl_xor(azz, o);
    }
    if (lane == 0) {
        const float2* p = (const float2*)(av6 + (size_t)a * 6);
        float2 p0 = p[0], p1 = p[1], p2 = p[2];
        axx += p0.x; axy += p0.y; axz += p1.x;
        ayy += p1.y; ayz += p2.x; azz += p2.y;
        float* o9 = out + OFF_AV + (size_t)a * 9;
        o9[0] = axx; o9[1] = axy; o9[2] = axz;
        o9[3] = axy; o9[4] = ayy; o9[5] = ayz;
        o9[6] = axz; o9[7] = ayz; o9[8] = azz;
    }
}

__global__ void virial_reduce(float* __restrict__ out) {
    const float* av = out + OFF_AV;
    float acc[9];
    #pragma unroll
    for (int c = 0; c < 9; ++c) acc[c] = 0.0f;
    for (int n = blockIdx.x * blockDim.x + threadIdx.x; n < N_ATOMS;
         n += gridDim.x * blockDim.x) {
        #pragma unroll
        for (int c = 0; c < 9; ++c) acc[c] += av[n*9 + c];
    }
    __shared__ float red[4];
    int lane = threadIdx.x & 63, wid = threadIdx.x >> 6;
    #pragma unroll
    for (int c = 0; c < 9; ++c) {
        float v = acc[c];
        #pragma unroll
        for (int o = 32; o > 0; o >>= 1) v += __shfl_down(v, o);
        if (lane == 0) red[wid] = v;
        __syncthreads();
        if (threadIdx.x == 0) atomicAdd(&out[OFF_VIR + c], red[0]+red[1]+red[2]+red[3]);
        __syncthreads();
    }
}

// ---------------- launch ----------------

extern "C" void kernel_launch(void* const* d_in, const int* in_sizes, int n_in,
                              void* d_out, int out_size, void* d_ws, size_t ws_size,
                              hipStream_t stream) {
    const float* positions = (const float*)d_in[0];
    const float* vectors   = (const float*)d_in[1];
    const float* lg        = (const float*)d_in[2];
    const float* W1        = (const float*)d_in[3];
    const float* b1        = (const float*)d_in[4];
    const float* W2        = (const float*)d_in[5];
    const float* w3        = (const float*)d_in[6];
    const float* field     = (const float*)d_in[7];
    const float* alphas    = (const float*)d_in[8];
    const int*   edge_index= (const int*)  d_in[9];
    float* out = (float*)d_out;
    int*   wsi = (int*)d_ws;
    float* wsf = (float*)d_ws;

    dim3 blk(256);
    dim3 egrid((N_EDGES + 255) / 256);     // 12500
    dim3 g16(NBLK16);                      // 6250 blocks, 16 lanes/atom

    if (ws_size >= (size_t)NEND * 4) {
        float*  s_tab  = wsf + NTAB_S;
        float*  g_tab  = wsf + NTAB_G;
        int*    offs_r = wsi + NOFF_R;
        int*    cnt_r8 = wsi + NCNT_R8;
        float*  tepart = wsf + NTEP;
        float*  vpart  = wsf + NVPART;
        float*  av6s   = wsf + NAV6S;
        float4* pay_r  = (float4*)(wsf + NPAY_R);
        int*    bsum   = wsi + NBSUM;      // aliases pay_r head (dead before scatter)

        // offs_r + cnt_r8 contiguous: one memset; av6s zeroed separately
        hipMemsetAsync(offs_r, 0, (size_t)9 * WPAD * sizeof(int), stream);
        hipMemsetAsync(av6s, 0, (size_t)48 * N_ATOMS * sizeof(float), stream);

        build_tables<<<dim3(NB*HIDDEN/256), blk, 0, stream>>>(W1, b1, alphas, s_tab, g_tab);
        count8_r<<<egrid, blk, 0, stream>>>(edge_index, cnt_r8);
        xcd_prefix_r<<<dim3((N_ATOMS+255)/256), blk, 0, stream>>>(cnt_r8, offs_r);
        scanA<<<dim3(SCAN_NB), dim3(SCAN_B), 0, stream>>>(offs_r, bsum);
        scanB<<<dim3(1), dim3(128), 0, stream>>>(bsum);
        scanC<<<dim3(SCAN_NB), dim3(SCAN_B), 0, stream>>>(offs_r, bsum);
        scatter_r<<<egrid, blk, 0, stream>>>(edge_index, offs_r, cnt_r8, vectors, pay_r);
        fused16<<<g16, blk, 0, stream>>>(pay_r, positions, lg, W2, w3, field,
                                         offs_r, s_tab, g_tab, av6s, tepart, out);
        av_finalize<<<dim3(AVBLK), blk, 0, stream>>>(av6s, vpart, out);
        finalize_kernel<<<dim3(1), dim3(1024), 0, stream>>>(tepart, vpart, out);
    } else {
        // fallback: round-3 verified path (67.2 MB ws)
        int*   offs_r = wsi + WOFF_OFFS_R;
        int*   offs_s = wsi + WOFF_OFFS_S;
        int*   rank_r = wsi + WOFF_RANK_R;
        int*   rank_s = wsi + WOFF_RANK_S;
        int*   eid_r  = wsi + WOFF_EID_R;
        int*   eid_s  = wsi + WOFF_EID_S;
        float* dr2buf = wsf + WOFF_DR2;
        float* av6    = wsf + WOFF_AV6;
        dim3 agrid(N_ATOMS / 4);

        hipMemsetAsync(offs_r, 0, (size_t)2 * WPAD * sizeof(int), stream);
        hipMemsetAsync(out + OFF_TE, 0, sizeof(float), stream);
        hipMemsetAsync(out + OFF_VIR, 0, 9 * sizeof(float), stream);

        count_kernel<<<egrid, blk, 0, stream>>>(edge_index, offs_r, offs_s, rank_r, rank_s);
        scan_kernel<<<dim3(2), blk, 0, stream>>>(offs_r, offs_s);
        scatter_kernel<<<egrid, blk, 0, stream>>>(edge_index, offs_r, offs_s,
                                                  rank_r, rank_s, eid_r, eid_s);
        fused_kernel<<<agrid, blk, 0, stream>>>(vectors, positions, lg, W1, b1, W2, w3,
                                                field, alphas, offs_r, eid_r, dr2buf, av6, out);
        bwd_send_kernel<<<agrid, blk, 0, stream>>>(vectors, offs_s, eid_s, dr2buf, av6, out);
        virial_reduce<<<dim3(256), blk, 0, stream>>>(out);
    }
}

// Round 9
// 1210.245 us; speedup vs baseline: 1.0926x; 1.0926x over previous
//
#include <hip/hip_runtime.h>

#define N_ATOMS 100000
#define N_EDGES 3200000
#define N_RBF 8
#define HIDDEN 16

#define NB 4096
#define TSCALE 64.0f   // bins per unit r2; table covers r2 in [0, 64)

// fixed-point scale for i64 virial accumulation (exact: *2^32 is an exponent shift)
#define FPSCALE 4294967296.0f
#define FPINV   2.3283064365386963e-10

// d_out layout (floats):
#define OFF_TE   0
#define OFF_NE   1
#define OFF_F    (1 + N_ATOMS)
#define OFF_VIR  (1 + N_ATOMS + 3*N_ATOMS)
#define OFF_AV   (OFF_VIR + 9)

#define WPAD (N_ATOMS + 4)
#define NBLK16 (N_ATOMS / 16)                   // 6250 blocks in fused16
#define AVBLK ((N_ATOMS + 255) / 256)           // 391 blocks in av_finalize
#define SCAN_B 1024
#define SCAN_NB ((N_ATOMS + SCAN_B) / SCAN_B)   // 98 blocks cover N_ATOMS+1

// ---- new-path ws layout (words) ----
#define NTAB_S   0
#define NTAB_G   (NB*HIDDEN)
#define NOFF_R   (2*NB*HIDDEN)                // 131072
#define NCNT_R8  (NOFF_R + WPAD)
#define NTEP     (NCNT_R8 + 8*WPAD)
#define NVPART   (NTEP + 8192)
#define NAV6R    (NVPART + 4096)              // recv-side float partials, 6*N
#define NAV6S64  (NAV6R + 6*N_ATOMS)          // 8 per-XCD i64 accumulators (4.8MB each)
#define NPAY_R   (NAV6S64 + 2*48*N_ATOMS)     // word off 11,243,396 (16B aligned)
#define NBSUM    NPAY_R                       // scan temp aliases pay_r head
#define NEND     (NPAY_R + 4*N_EDGES)         // 24,043,396 words = 96.2 MB

// ---- fallback (round-3) ws layout ----
#define WOFF_OFFS_R 0
#define WOFF_OFFS_S WPAD
#define WOFF_RANK_R (2*WPAD)
#define WOFF_RANK_S (WOFF_RANK_R + N_EDGES)
#define WOFF_EID_R  (WOFF_RANK_S + N_EDGES)
#define WOFF_EID_S  (WOFF_EID_R + N_EDGES)
#define WOFF_DR2    (WOFF_EID_S + N_EDGES)
#define WOFF_AV6    (WOFF_DR2 + N_EDGES)
#define WOFF_END    (WOFF_AV6 + 6*N_ATOMS)

__device__ inline unsigned int get_xcd() {
    unsigned int xcd;
    asm volatile("s_getreg_b32 %0, hwreg(HW_REG_XCC_ID)" : "=s"(xcd));
    return xcd & 7;
}

__device__ inline void l2_atomic_addi64(long long* p, float v) {
    long long q = (long long)(v * FPSCALE);
    __hip_atomic_fetch_add(p, q, __ATOMIC_RELAXED, __HIP_MEMORY_SCOPE_WORKGROUP);
}

// ---------------- table build ----------------
__global__ void build_tables(const float* __restrict__ W1, const float* __restrict__ b1,
                             const float* __restrict__ alphas,
                             float* __restrict__ s_tab, float* __restrict__ g_tab) {
    int idx = blockIdx.x * blockDim.x + threadIdx.x;   // NB*HIDDEN = 65536
    int b = idx >> 4, j = idx & 15;
    float r2 = (float)b / TSCALE;
    float pre = b1[j], pw = 0.f;
    #pragma unroll
    for (int f = 0; f < N_RBF; ++f) {
        float al = alphas[f];
        float ph = __expf(-r2 * al);
        float w  = W1[f*HIDDEN + j];
        pre += ph * w;
        pw  += al * ph * w;
    }
    float sig = 1.f / (1.f + __expf(-pre));
    s_tab[idx] = pre * sig;
    g_tab[idx] = sig * (1.f + pre * (1.f - sig)) * pw;
}

// ---------------- CSR build (recv only): per-XCD histogram, L2-local ----------------

__global__ void count8_r(const int* __restrict__ ei, int* __restrict__ cnt_r8) {
    unsigned int xcd = get_xcd();
    int e = blockIdx.x * blockDim.x + threadIdx.x;
    if (e >= N_EDGES) return;
    int recv = ei[N_EDGES + e];
    __hip_atomic_fetch_add(&cnt_r8[xcd * WPAD + recv], 1,
                           __ATOMIC_RELAXED, __HIP_MEMORY_SCOPE_WORKGROUP);
}

__global__ void xcd_prefix_r(int* __restrict__ cnt_r8, int* __restrict__ offs_r) {
    int a = blockIdx.x * blockDim.x + threadIdx.x;
    if (a >= N_ATOMS) return;
    int t = 0;
    #pragma unroll
    for (int x = 0; x < 8; ++x) {
        int c = cnt_r8[x*WPAD + a];
        cnt_r8[x*WPAD + a] = t;
        t += c;
    }
    offs_r[a] = t;
}

// ---------------- parallel 3-phase exclusive scan over N_ATOMS+1 ----------------

__global__ void scanA(int* __restrict__ a, int* __restrict__ bsum) {
    const int n = N_ATOMS + 1;
    int i = blockIdx.x * SCAN_B + threadIdx.x;
    int v = (i < n) ? a[i] : 0;
    int lane = threadIdx.x & 63, w = threadIdx.x >> 6;
    int s = v;
    #pragma unroll
    for (int o = 1; o < 64; o <<= 1) {
        int t = __shfl_up(s, o);
        if (lane >= o) s += t;
    }
    __shared__ int wsum[16];
    if (lane == 63) wsum[w] = s;
    __syncthreads();
    if (threadIdx.x < 16) {
        int sc = wsum[threadIdx.x];
        #pragma unroll
        for (int o = 1; o < 16; o <<= 1) {
            int t = __shfl_up(sc, o);
            if ((int)threadIdx.x >= o) sc += t;
        }
        wsum[threadIdx.x] = sc;
    }
    __syncthreads();
    int wpre = (w > 0) ? wsum[w-1] : 0;
    if (i < n) a[i] = s - v + wpre;
    if (threadIdx.x == 0) bsum[blockIdx.x] = wsum[15];
}

__global__ void scanB(int* __restrict__ bsum) {
    __shared__ int lds[SCAN_NB];
    if (threadIdx.x < SCAN_NB) lds[threadIdx.x] = bsum[threadIdx.x];
    __syncthreads();
    if (threadIdx.x == 0) {
        int run = 0;
        for (int i = 0; i < SCAN_NB; ++i) { int t = lds[i]; lds[i] = run; run += t; }
    }
    __syncthreads();
    if (threadIdx.x < SCAN_NB) bsum[threadIdx.x] = lds[threadIdx.x];
}

__global__ void scanC(int* __restrict__ a, const int* __restrict__ bsum) {
    int i = blockIdx.x * SCAN_B + threadIdx.x;
    if (i < N_ATOMS + 1) a[i] += bsum[blockIdx.x];
}

// ---------------- scatter (recv only): allocator-style, PLAIN stores ----------------
// pay_r[rs] = (vx,vy,vz, bitcast(send_atom)). Plain stores merge in the local
// XCD's write-back L2 (per-XCD contiguous sub-ranges per atom bucket).
__global__ void scatter_r(const int* __restrict__ ei,
                          const int* __restrict__ offs_r, int* __restrict__ cnt_r8,
                          const float* __restrict__ vectors,
                          float4* __restrict__ pay_r) {
    unsigned int xcd = get_xcd();
    int e = blockIdx.x * blockDim.x + threadIdx.x;
    if (e >= N_EDGES) return;
    int send = ei[e], recv = ei[N_EDGES + e];
    int br = __hip_atomic_fetch_add(&cnt_r8[xcd*WPAD + recv], 1,
                                    __ATOMIC_RELAXED, __HIP_MEMORY_SCOPE_WORKGROUP);
    int rs = offs_r[recv] + br;
    float vx = vectors[3*e], vy = vectors[3*e+1], vz = vectors[3*e+2];
    pay_r[rs] = make_float4(vx, vy, vz, __int_as_float(send));
}

// ---------------- fused: fwd + node MLP + bwd; send virial via i64 L2 atomics ----

__global__ void fused16(const float4* __restrict__ pay_r,
                        const float* __restrict__ positions,
                        const float* __restrict__ lg,
                        const float* __restrict__ W2, const float* __restrict__ w3,
                        const float* __restrict__ field,
                        const int* __restrict__ offs_r,
                        const float* __restrict__ s_tab, const float* __restrict__ g_tab,
                        long long* __restrict__ av6s, float* __restrict__ av6r,
                        float* __restrict__ tepart, float* __restrict__ out) {
    unsigned int xcd = get_xcd();
    long long* avx = av6s + (size_t)xcd * 6 * N_ATOMS;
    int tid = blockIdx.x * blockDim.x + threadIdx.x;
    int a = tid >> 4;
    int sl = threadIdx.x & 15;
    int lane = threadIdx.x & 63;
    int gb = lane & 48;
    int start = offs_r[a], end = offs_r[a + 1];
    int k0 = start + sl;

    float m[HIDDEN];
    #pragma unroll
    for (int j = 0; j < HIDDEN; ++j) m[j] = 0.f;

    // ---- pass 1: forward via S-table ----
    for (int k = k0; k < end; k += 16) {
        float4 p = pay_r[k];
        float r2 = p.x*p.x + p.y*p.y + p.z*p.z;
        float x = fminf(r2 * TSCALE, (float)(NB - 2) + 0.999f);
        int i = (int)x;
        float f = x - (float)i;
        const float4* r0 = (const float4*)(s_tab + i * HIDDEN);
        const float4* r1 = (const float4*)(s_tab + (i + 1) * HIDDEN);
        #pragma unroll
        for (int q = 0; q < 4; ++q) {
            float4 A = r0[q], B = r1[q];
            m[4*q+0] += A.x + f * (B.x - A.x);
            m[4*q+1] += A.y + f * (B.y - A.y);
            m[4*q+2] += A.z + f * (B.z - A.z);
            m[4*q+3] += A.w + f * (B.w - A.w);
        }
    }

    #pragma unroll
    for (int o = 1; o < 16; o <<= 1) {
        #pragma unroll
        for (int j = 0; j < HIDDEN; ++j) m[j] += __shfl_xor(m[j], o);
    }

    // ---- node MLP, channel j = sl per lane ----
    float aj = 0.f;
    #pragma unroll
    for (int i = 0; i < HIDDEN; ++i) aj += m[i] * W2[i*HIDDEN + sl];
    float sigj = 1.f / (1.f + __expf(-aj));
    float l = lg[a];
    float w3j = w3[sl];
    float sd = aj * sigj * w3j;
    #pragma unroll
    for (int o = 1; o < 16; o <<= 1) sd += __shfl_xor(sd, o);
    float dAj = l * w3j * sigj * (1.f + aj * (1.f - sigj));
    float gown = 0.f;
    #pragma unroll
    for (int q = 0; q < HIDDEN; ++q) {
        float dq = __shfl(dAj, gb | q);
        gown += dq * W2[sl*HIDDEN + q];
    }
    float g[HIDDEN];
    #pragma unroll
    for (int q = 0; q < HIDDEN; ++q) g[q] = __shfl(gown, gb | q);

    float contrib = 0.f;
    if (sl == 0) {
        float ne = sd + positions[3*a]*field[0] + positions[3*a+1]*field[1]
                      + positions[3*a+2]*field[2];
        out[OFF_NE + a] = ne;
        out[OFF_F + 3*a + 0] = -l * field[0];
        out[OFF_F + 3*a + 1] = -l * field[1];
        out[OFF_F + 3*a + 2] = -l * field[2];
        contrib = ne * l;
    }

    // ---- pass 2: backward via G-table; send virial via i64 fixed-point L2 atomics ----
    float axx=0.f, axy=0.f, axz=0.f, ayy=0.f, ayz=0.f, azz=0.f;
    for (int k = k0; k < end; k += 16) {
        float4 p = pay_r[k];
        float r2 = p.x*p.x + p.y*p.y + p.z*p.z;
        float x = fminf(r2 * TSCALE, (float)(NB - 2) + 0.999f);
        int i = (int)x;
        float f = x - (float)i;
        const float4* r0 = (const float4*)(g_tab + i * HIDDEN);
        const float4* r1 = (const float4*)(g_tab + (i + 1) * HIDDEN);
        float dr2 = 0.f;
        #pragma unroll
        for (int q = 0; q < 4; ++q) {
            float4 A = r0[q], B = r1[q];
            dr2 -= g[4*q+0] * (A.x + f * (B.x - A.x));
            dr2 -= g[4*q+1] * (A.y + f * (B.y - A.y));
            dr2 -= g[4*q+2] * (A.z + f * (B.z - A.z));
            dr2 -= g[4*q+3] * (A.w + f * (B.w - A.w));
        }
        float txx = dr2*p.x*p.x, txy = dr2*p.x*p.y, txz = dr2*p.x*p.z;
        float tyy = dr2*p.y*p.y, tyz = dr2*p.y*p.z, tzz = dr2*p.z*p.z;
        int sa = __float_as_int(p.w);
        long long* b = avx + (size_t)sa * 6;
        l2_atomic_addi64(b+0, txx); l2_atomic_addi64(b+1, txy); l2_atomic_addi64(b+2, txz);
        l2_atomic_addi64(b+3, tyy); l2_atomic_addi64(b+4, tyz); l2_atomic_addi64(b+5, tzz);
        axx += txx; axy += txy; axz += txz;
        ayy += tyy; ayz += tyz; azz += tzz;
    }
    #pragma unroll
    for (int o = 1; o < 16; o <<= 1) {
        axx += __shfl_xor(axx, o); axy += __shfl_xor(axy, o); axz += __shfl_xor(axz, o);
        ayy += __shfl_xor(ayy, o); ayz += __shfl_xor(ayz, o); azz += __shfl_xor(azz, o);
    }
    if (sl == 0) {
        // recv-side partial: block owns atom a -> plain stores, no atomics
        float2* p = (float2*)(av6r + (size_t)a * 6);
        p[0] = make_float2(axx, axy);
        p[1] = make_float2(axz, ayy);
        p[2] = make_float2(ayz, azz);
    }

    // total-energy block partial (no global atomic)
    __shared__ float red[4];
    if (sl != 0) contrib = 0.f;
    contrib += __shfl_xor(contrib, 16);
    contrib += __shfl_xor(contrib, 32);
    int w = threadIdx.x >> 6;
    if (lane == 0) red[w] = contrib;
    __syncthreads();
    if (threadIdx.x == 0) tepart[blockIdx.x] = red[0]+red[1]+red[2]+red[3];
}

// -------- per-atom: sum 8 i64 replicas + recv floats -> atom_virial; block partials ----

__global__ void av_finalize(const long long* __restrict__ av6s,
                            const float* __restrict__ av6r,
                            float* __restrict__ vpart, float* __restrict__ out) {
    int a = blockIdx.x * blockDim.x + threadIdx.x;
    float s[6] = {0.f,0.f,0.f,0.f,0.f,0.f};
    if (a < N_ATOMS) {
        long long q[6] = {0,0,0,0,0,0};
        #pragma unroll
        for (int x = 0; x < 8; ++x) {
            const long long* p = av6s + (size_t)x*6*N_ATOMS + (size_t)a*6;
            #pragma unroll
            for (int c = 0; c < 6; ++c) q[c] += p[c];
        }
        const float2* r = (const float2*)(av6r + (size_t)a * 6);
        float2 r0 = r[0], r1 = r[1], r2 = r[2];
        s[0] = (float)((double)q[0] * FPINV) + r0.x;
        s[1] = (float)((double)q[1] * FPINV) + r0.y;
        s[2] = (float)((double)q[2] * FPINV) + r1.x;
        s[3] = (float)((double)q[3] * FPINV) + r1.y;
        s[4] = (float)((double)q[4] * FPINV) + r2.x;
        s[5] = (float)((double)q[5] * FPINV) + r2.y;
        float* o9 = out + OFF_AV + (size_t)a * 9;
        o9[0] = s[0]; o9[1] = s[1]; o9[2] = s[2];
        o9[3] = s[1]; o9[4] = s[3]; o9[5] = s[4];
        o9[6] = s[2]; o9[7] = s[4]; o9[8] = s[5];
    }
    int lane = threadIdx.x & 63, w = threadIdx.x >> 6;
    #pragma unroll
    for (int c = 0; c < 6; ++c) {
        #pragma unroll
        for (int o = 1; o < 64; o <<= 1) s[c] += __shfl_xor(s[c], o);
    }
    __shared__ float sh[4][6];
    if (lane == 0) {
        #pragma unroll
        for (int c = 0; c < 6; ++c) sh[w][c] = s[c];
    }
    __syncthreads();
    if (threadIdx.x < 6) {
        vpart[blockIdx.x * 6 + threadIdx.x] =
            sh[0][threadIdx.x] + sh[1][threadIdx.x] + sh[2][threadIdx.x] + sh[3][threadIdx.x];
    }
}

// -------- final reduce of TE + virial partials: one block, plain stores --------

__global__ void finalize_kernel(const float* __restrict__ tepart,
                                const float* __restrict__ vpart,
                                float* __restrict__ out) {
    int t = threadIdx.x;
    float acc[7];
    #pragma unroll
    for (int c = 0; c < 7; ++c) acc[c] = 0.f;
    for (int i = t; i < NBLK16; i += 1024) acc[0] += tepart[i];
    for (int i = t; i < AVBLK; i += 1024) {
        const float* p = vpart + (size_t)i * 6;
        acc[1] += p[0]; acc[2] += p[1]; acc[3] += p[2];
        acc[4] += p[3]; acc[5] += p[4]; acc[6] += p[5];
    }
    #pragma unroll
    for (int c = 0; c < 7; ++c) {
        #pragma unroll
        for (int o = 1; o < 64; o <<= 1) acc[c] += __shfl_xor(acc[c], o);
    }
    __shared__ float sh[16][8];
    int lane = t & 63, w = t >> 6;
    if (lane == 0) {
        #pragma unroll
        for (int c = 0; c < 7; ++c) sh[w][c] = acc[c];
    }
    __syncthreads();
    if (t == 0) {
        float s[7];
        #pragma unroll
        for (int c = 0; c < 7; ++c) {
            float v = 0.f;
            #pragma unroll
            for (int q = 0; q < 16; ++q) v += sh[q][c];
            s[c] = v;
        }
        out[OFF_TE] = s[0];
        out[OFF_VIR + 0] = s[1]; out[OFF_VIR + 1] = s[2]; out[OFF_VIR + 2] = s[3];
        out[OFF_VIR + 3] = s[2]; out[OFF_VIR + 4] = s[4]; out[OFF_VIR + 5] = s[5];
        out[OFF_VIR + 6] = s[3]; out[OFF_VIR + 7] = s[5]; out[OFF_VIR + 8] = s[6];
    }
}

// ================= fallback (round-3 verified path) =================

__global__ void count_kernel(const int* __restrict__ ei,
                             int* __restrict__ cnt_r, int* __restrict__ cnt_s,
                             int* __restrict__ rank_r, int* __restrict__ rank_s) {
    int e = blockIdx.x * blockDim.x + threadIdx.x;
    if (e >= N_EDGES) return;
    int send = ei[e], recv = ei[N_EDGES + e];
    rank_r[e] = atomicAdd(&cnt_r[recv], 1);
    rank_s[e] = atomicAdd(&cnt_s[send], 1);
}

__global__ void scan_kernel(int* __restrict__ offs_r, int* __restrict__ offs_s) {
    int* a = (blockIdx.x == 0) ? offs_r : offs_s;
    const int n = N_ATOMS + 1;
    __shared__ int wsum[4];
    __shared__ int carry_s;
    if (threadIdx.x == 0) carry_s = 0;
    __syncthreads();
    int lane = threadIdx.x & 63, w = threadIdx.x >> 6;
    for (int base = 0; base < n; base += 256) {
        int i = base + threadIdx.x;
        int v = (i < n) ? a[i] : 0;
        int s = v;
        #pragma unroll
        for (int o = 1; o < 64; o <<= 1) {
            int t = __shfl_up(s, o);
            if (lane >= o) s += t;
        }
        if (lane == 63) wsum[w] = s;
        __syncthreads();
        int wpre = 0;
        for (int k = 0; k < w; ++k) wpre += wsum[k];
        int incl = s + wpre;
        int total = wsum[0] + wsum[1] + wsum[2] + wsum[3];
        int excl = incl - v + carry_s;
        if (i < n) a[i] = excl;
        __syncthreads();
        if (threadIdx.x == 0) carry_s += total;
        __syncthreads();
    }
}

__global__ void scatter_kernel(const int* __restrict__ ei,
                               const int* __restrict__ offs_r, const int* __restrict__ offs_s,
                               const int* __restrict__ rank_r, const int* __restrict__ rank_s,
                               int* __restrict__ eid_r, int* __restrict__ eid_s) {
    int e = blockIdx.x * blockDim.x + threadIdx.x;
    if (e >= N_EDGES) return;
    int send = ei[e], recv = ei[N_EDGES + e];
    eid_r[offs_r[recv] + rank_r[e]] = e;
    eid_s[offs_s[send] + rank_s[e]] = e;
}

__global__ void fused_kernel(const float* __restrict__ vectors,
                             const float* __restrict__ positions,
                             const float* __restrict__ lg,
                             const float* __restrict__ W1, const float* __restrict__ b1,
                             const float* __restrict__ W2, const float* __restrict__ w3,
                             const float* __restrict__ field, const float* __restrict__ alphas,
                             const int* __restrict__ offs_r, const int* __restrict__ eid_r,
                             float* __restrict__ dr2buf, float* __restrict__ av6,
                             float* __restrict__ out) {
    int a = (blockIdx.x * blockDim.x + threadIdx.x) >> 6;
    int lane = threadIdx.x & 63;
    int start = offs_r[a], end = offs_r[a + 1];
    float al[N_RBF];
    #pragma unroll
    for (int f = 0; f < N_RBF; ++f) al[f] = alphas[f];
    float m[HIDDEN];
    #pragma unroll
    for (int j = 0; j < HIDDEN; ++j) m[j] = 0.f;
    float t[HIDDEN], paw[HIDDEN];
    float vx0 = 0.f, vy0 = 0.f, vz0 = 0.f;
    int e0 = -1;
    int k0 = start + lane;
    for (int k = k0; k < end; k += 64) {
        int e = eid_r[k];
        float vx = vectors[3*e], vy = vectors[3*e+1], vz = vectors[3*e+2];
        float r2 = vx*vx + vy*vy + vz*vz;
        float phi[N_RBF], apf[N_RBF];
        #pragma unroll
        for (int f = 0; f < N_RBF; ++f) { phi[f] = __expf(-r2 * al[f]); apf[f] = al[f] * phi[f]; }
        bool first = (k == k0);
        if (first) { e0 = e; vx0 = vx; vy0 = vy; vz0 = vz; }
        #pragma unroll
        for (int j = 0; j < HIDDEN; ++j) {
            float pre = b1[j];
            float pw = 0.f;
            #pragma unroll
            for (int f = 0; f < N_RBF; ++f) {
                float w = W1[f*HIDDEN + j];
                pre += phi[f] * w;
                pw  += apf[f] * w;
            }
            float sig = 1.f / (1.f + __expf(-pre));
            m[j] += pre * sig;
            if (first) { t[j] = sig * (1.f + pre * (1.f - sig)); paw[j] = pw; }
        }
    }
    #pragma unroll
    for (int o = 1; o < 64; o <<= 1) {
        #pragma unroll
        for (int j = 0; j < HIDDEN; ++j) m[j] += __shfl_xor(m[j], o);
    }
    int jj = lane & 15;
    int gbase = lane & 48;
    float aj = 0.f;
    #pragma unroll
    for (int i = 0; i < HIDDEN; ++i) aj += m[i] * W2[i*HIDDEN + jj];
    float sigj = 1.f / (1.f + __expf(-aj));
    float l = lg[a];
    float sd = aj * sigj * w3[jj];
    #pragma unroll
    for (int o = 1; o < 16; o <<= 1) sd += __shfl_xor(sd, o);
    float dAj = l * w3[jj] * sigj * (1.f + aj * (1.f - sigj));
    float dAv[HIDDEN];
    #pragma unroll
    for (int q = 0; q < HIDDEN; ++q) dAv[q] = __shfl(dAj, gbase | q);
    float gown = 0.f;
    #pragma unroll
    for (int j2 = 0; j2 < HIDDEN; ++j2) gown += dAv[j2] * W2[jj*HIDDEN + j2];
    float g[HIDDEN];
    #pragma unroll
    for (int q = 0; q < HIDDEN; ++q) g[q] = __shfl(gown, gbase | q);
    float contrib = 0.f;
    if (lane == 0) {
        float ne = sd + positions[3*a]*field[0] + positions[3*a+1]*field[1]
                      + positions[3*a+2]*field[2];
        out[OFF_NE + a] = ne;
        out[OFF_F + 3*a + 0] = -l * field[0];
        out[OFF_F + 3*a + 1] = -l * field[1];
        out[OFF_F + 3*a + 2] = -l * field[2];
        contrib = ne * l;
    }
    float axx=0.f, axy=0.f, axz=0.f, ayy=0.f, ayz=0.f, azz=0.f;
    if (k0 < end) {
        float dr2 = 0.f;
        #pragma unroll
        for (int j = 0; j < HIDDEN; ++j) dr2 -= (g[j] * t[j]) * paw[j];
        dr2buf[e0] = dr2;
        axx = dr2*vx0*vx0; axy = dr2*vx0*vy0; axz = dr2*vx0*vz0;
        ayy = dr2*vy0*vy0; ayz = dr2*vy0*vz0; azz = dr2*vz0*vz0;
    }
    for (int k = k0 + 64; k < end; k += 64) {
        int e = eid_r[k];
        float vx = vectors[3*e], vy = vectors[3*e+1], vz = vectors[3*e+2];
        float r2 = vx*vx + vy*vy + vz*vz;
        float phi[N_RBF], apf[N_RBF];
        #pragma unroll
        for (int f = 0; f < N_RBF; ++f) { phi[f] = __expf(-r2 * al[f]); apf[f] = al[f] * phi[f]; }
        float dr2 = 0.f;
        #pragma unroll
        for (int j = 0; j < HIDDEN; ++j) {
            float pre = b1[j];
            float pw = 0.f;
            #pragma unroll
            for (int f = 0; f < N_RBF; ++f) {
                float w = W1[f*HIDDEN + j];
                pre += phi[f] * w;
                pw  += apf[f] * w;
            }
            float sig = 1.f / (1.f + __expf(-pre));
            float tt = sig * (1.f + pre * (1.f - sig));
            dr2 -= (g[j] * tt) * pw;
        }
        dr2buf[e] = dr2;
        axx += dr2*vx*vx; axy += dr2*vx*vy; axz += dr2*vx*vz;
        ayy += dr2*vy*vy; ayz += dr2*vy*vz; azz += dr2*vz*vz;
    }
    #pragma unroll
    for (int o = 1; o < 64; o <<= 1) {
        axx += __shfl_xor(axx, o); axy += __shfl_xor(axy, o); axz += __shfl_xor(axz, o);
        ayy += __shfl_xor(ayy, o); ayz += __shfl_xor(ayz, o); azz += __shfl_xor(azz, o);
    }
    if (lane == 0) {
        float2* p = (float2*)(av6 + (size_t)a * 6);
        p[0] = make_float2(axx, axy);
        p[1] = make_float2(axz, ayy);
        p[2] = make_float2(ayz, azz);
    }
    __shared__ float red[4];
    int w = threadIdx.x >> 6;
    if (lane == 0) red[w] = contrib;
    __syncthreads();
    if (threadIdx.x == 0) atomicAdd(&out[OFF_TE], red[0]+red[1]+red[2]+red[3]);
}

__global__ void bwd_send_kernel(const float* __restrict__ vectors,
                                const int* __restrict__ offs_s, const int* __restrict__ eid_s,
                                const float* __restrict__ dr2buf, const float* __restrict__ av6,
                                float* __restrict__ out) {
    int a = (blockIdx.x * blockDim.x + threadIdx.x) >> 6;
    int lane = threadIdx.x & 63;
    int start = offs_s[a], end = offs_s[a + 1];
    float axx=0.f, axy=0.f, axz=0.f, ayy=0.f, ayz=0.f, azz=0.f;
    for (int k = start + lane; k < end; k += 64) {
        int e = eid_s[k];
        float dr2 = dr2buf[e];
        float vx = vectors[3*e], vy = vectors[3*e+1], vz = vectors[3*e+2];
        axx += dr2*vx*vx; axy += dr2*vx*vy; axz += dr2*vx*vz;
        ayy += dr2*vy*vy; ayz += dr2*vy*vz; azz += dr2*vz*vz;
    }
    #pragma unroll
    for (int o = 1; o < 64; o <<= 1) {
        axx += __shfl_xor(axx, o); axy += __shfl_xor(axy, o); axz += __shfl_xor(axz, o);
        ayy += __shfl_xor(ayy, o); ayz += __shfl_xor(ayz, o); azz += __shfl_xor(azz, o);
    }
    if (lane == 0) {
        const float2* p = (const float2*)(av6 + (size_t)a * 6);
        float2 p0 = p[0], p1 = p[1], p2 = p[2];
        axx += p0.x; axy += p0.y; axz += p1.x;
        ayy += p1.y; ayz += p2.x; azz += p2.y;
        float* o9 = out + OFF_AV + (size_t)a * 9;
        o9[0] = axx; o9[1] = axy; o9[2] = axz;
        o9[3] = axy; o9[4] = ayy; o9[5] = ayz;
        o9[6] = axz; o9[7] = ayz; o9[8] = azz;
    }
}

__global__ void virial_reduce(float* __restrict__ out) {
    const float* av = out + OFF_AV;
    float acc[9];
    #pragma unroll
    for (int c = 0; c < 9; ++c) acc[c] = 0.0f;
    for (int n = blockIdx.x * blockDim.x + threadIdx.x; n < N_ATOMS;
         n += gridDim.x * blockDim.x) {
        #pragma unroll
        for (int c = 0; c < 9; ++c) acc[c] += av[n*9 + c];
    }
    __shared__ float red[4];
    int lane = threadIdx.x & 63, wid = threadIdx.x >> 6;
    #pragma unroll
    for (int c = 0; c < 9; ++c) {
        float v = acc[c];
        #pragma unroll
        for (int o = 32; o > 0; o >>= 1) v += __shfl_down(v, o);
        if (lane == 0) red[wid] = v;
        __syncthreads();
        if (threadIdx.x == 0) atomicAdd(&out[OFF_VIR + c], red[0]+red[1]+red[2]+red[3]);
        __syncthreads();
    }
}

// ---------------- launch ----------------

extern "C" void kernel_launch(void* const* d_in, const int* in_sizes, int n_in,
                              void* d_out, int out_size, void* d_ws, size_t ws_size,
                              hipStream_t stream) {
    const float* positions = (const float*)d_in[0];
    const float* vectors   = (const float*)d_in[1];
    const float* lg        = (const float*)d_in[2];
    const float* W1        = (const float*)d_in[3];
    const float* b1        = (const float*)d_in[4];
    const float* W2        = (const float*)d_in[5];
    const float* w3        = (const float*)d_in[6];
    const float* field     = (const float*)d_in[7];
    const float* alphas    = (const float*)d_in[8];
    const int*   edge_index= (const int*)  d_in[9];
    float* out = (float*)d_out;
    int*   wsi = (int*)d_ws;
    float* wsf = (float*)d_ws;

    dim3 blk(256);
    dim3 egrid((N_EDGES + 255) / 256);     // 12500
    dim3 g16(NBLK16);                      // 6250 blocks, 16 lanes/atom

    if (ws_size >= (size_t)NEND * 4) {
        float*     s_tab  = wsf + NTAB_S;
        float*     g_tab  = wsf + NTAB_G;
        int*       offs_r = wsi + NOFF_R;
        int*       cnt_r8 = wsi + NCNT_R8;
        float*     tepart = wsf + NTEP;
        float*     vpart  = wsf + NVPART;
        float*     av6r   = wsf + NAV6R;
        long long* av6s   = (long long*)(wsf + NAV6S64);
        float4*    pay_r  = (float4*)(wsf + NPAY_R);
        int*       bsum   = wsi + NBSUM;   // aliases pay_r head (dead before scatter)

        // offs_r + cnt_r8 contiguous; av6r + av6s contiguous
        hipMemsetAsync(offs_r, 0, (size_t)9 * WPAD * sizeof(int), stream);
        hipMemsetAsync(av6r, 0, ((size_t)6*N_ATOMS + (size_t)96*N_ATOMS) * sizeof(float),
                       stream);

        build_tables<<<dim3(NB*HIDDEN/256), blk, 0, stream>>>(W1, b1, alphas, s_tab, g_tab);
        count8_r<<<egrid, blk, 0, stream>>>(edge_index, cnt_r8);
        xcd_prefix_r<<<dim3((N_ATOMS+255)/256), blk, 0, stream>>>(cnt_r8, offs_r);
        scanA<<<dim3(SCAN_NB), dim3(SCAN_B), 0, stream>>>(offs_r, bsum);
        scanB<<<dim3(1), dim3(128), 0, stream>>>(bsum);
        scanC<<<dim3(SCAN_NB), dim3(SCAN_B), 0, stream>>>(offs_r, bsum);
        scatter_r<<<egrid, blk, 0, stream>>>(edge_index, offs_r, cnt_r8, vectors, pay_r);
        fused16<<<g16, blk, 0, stream>>>(pay_r, positions, lg, W2, w3, field,
                                         offs_r, s_tab, g_tab, av6s, av6r, tepart, out);
        av_finalize<<<dim3(AVBLK), blk, 0, stream>>>(av6s, av6r, vpart, out);
        finalize_kernel<<<dim3(1), dim3(1024), 0, stream>>>(tepart, vpart, out);
    } else {
        // fallback: round-3 verified path (67.2 MB ws)
        int*   offs_r = wsi + WOFF_OFFS_R;
        int*   offs_s = wsi + WOFF_OFFS_S;
        int*   rank_r = wsi + WOFF_RANK_R;
        int*   rank_s = wsi + WOFF_RANK_S;
        int*   eid_r  = wsi + WOFF_EID_R;
        int*   eid_s  = wsi + WOFF_EID_S;
        float* dr2buf = wsf + WOFF_DR2;
        float* av6    = wsf + WOFF_AV6;
        dim3 agrid(N_ATOMS / 4);

        hipMemsetAsync(offs_r, 0, (size_t)2 * WPAD * sizeof(int), stream);
        hipMemsetAsync(out + OFF_TE, 0, sizeof(float), stream);
        hipMemsetAsync(out + OFF_VIR, 0, 9 * sizeof(float), stream);

        count_kernel<<<egrid, blk, 0, stream>>>(edge_index, offs_r, offs_s, rank_r, rank_s);
        scan_kernel<<<dim3(2), blk, 0, stream>>>(offs_r, offs_s);
        scatter_kernel<<<egrid, blk, 0, stream>>>(edge_index, offs_r, offs_s,
                                                  rank_r, rank_s, eid_r, eid_s);
        fused_kernel<<<agrid, blk, 0, stream>>>(vectors, positions, lg, W1, b1, W2, w3,
                                                field, alphas, offs_r, eid_r, dr2buf, av6, out);
        bwd_send_kernel<<<agrid, blk, 0, stream>>>(vectors, offs_s, eid_s, dr2buf, av6, out);
        virial_reduce<<<dim3(256), blk, 0, stream>>>(out);
    }
}

// Round 10
// 734.897 us; speedup vs baseline: 1.7993x; 1.6468x over previous
//
#include <hip/hip_runtime.h>

#define N_ATOMS 100000
#define N_EDGES 3200000
#define N_RBF 8
#define HIDDEN 16

#define NB 4096
#define TSCALE 64.0f   // bins per unit r2; table covers r2 in [0, 64)

// d_out layout (floats):
#define OFF_TE   0
#define OFF_NE   1
#define OFF_F    (1 + N_ATOMS)
#define OFF_VIR  (1 + N_ATOMS + 3*N_ATOMS)
#define OFF_AV   (OFF_VIR + 9)

#define WPAD (N_ATOMS + 4)
#define NBLK16 (N_ATOMS / 16)                   // 6250 blocks in fused16/bwd_send16
#define SCAN_B 1024
#define SCAN_NB ((N_ATOMS + SCAN_B) / SCAN_B)   // 98 blocks cover N_ATOMS+1

// ---- new-path ws layout (words) ----
#define NTAB_S   0
#define NTAB_G   (NB*HIDDEN)
#define NOFF_R   (2*NB*HIDDEN)                 // 131072
#define NOFF_S   (NOFF_R + WPAD)
#define NCNT_R8  (NOFF_S + WPAD)               // 8 per-XCD histograms (recv)
#define NCNT_S8  (NCNT_R8 + 8*WPAD)            // 8 per-XCD histograms (send)
#define NTEP     (NCNT_S8 + 8*WPAD)            // 1,931,144
#define NVPART   (NTEP + 8192)
#define NAV6R    (NVPART + 40960)              // recv-side float partials, 6*N
#define NPAY_R   (NAV6R + 6*N_ATOMS)           // 2,580,296 (16B aligned)
#define NDR2V    (NPAY_R + 4*N_EDGES)          // 15,380,296 (16B aligned)
#define NBSUM    NPAY_R                        // scan temp aliases pay_r head
#define NEND     (NDR2V + 4*N_EDGES)           // 28,180,296 words = 112.7 MB

// ---- fallback (round-3) ws layout ----
#define WOFF_OFFS_R 0
#define WOFF_OFFS_S WPAD
#define WOFF_RANK_R (2*WPAD)
#define WOFF_RANK_S (WOFF_RANK_R + N_EDGES)
#define WOFF_EID_R  (WOFF_RANK_S + N_EDGES)
#define WOFF_EID_S  (WOFF_EID_R + N_EDGES)
#define WOFF_DR2    (WOFF_EID_S + N_EDGES)
#define WOFF_AV6    (WOFF_DR2 + N_EDGES)
#define WOFF_END    (WOFF_AV6 + 6*N_ATOMS)

typedef float fvec4 __attribute__((ext_vector_type(4)));

__device__ inline void nt_store4(float a, float b, float c, float d, float4* p) {
    fvec4 t;
    t.x = a; t.y = b; t.z = c; t.w = d;
    __builtin_nontemporal_store(t, (fvec4*)p);
}

__device__ inline unsigned int get_xcd() {
    unsigned int xcd;
    asm volatile("s_getreg_b32 %0, hwreg(HW_REG_XCC_ID)" : "=s"(xcd));
    return xcd & 7;
}

// ---------------- table build ----------------
__global__ void build_tables(const float* __restrict__ W1, const float* __restrict__ b1,
                             const float* __restrict__ alphas,
                             float* __restrict__ s_tab, float* __restrict__ g_tab) {
    int idx = blockIdx.x * blockDim.x + threadIdx.x;   // NB*HIDDEN = 65536
    int b = idx >> 4, j = idx & 15;
    float r2 = (float)b / TSCALE;
    float pre = b1[j], pw = 0.f;
    #pragma unroll
    for (int f = 0; f < N_RBF; ++f) {
        float al = alphas[f];
        float ph = __expf(-r2 * al);
        float w  = W1[f*HIDDEN + j];
        pre += ph * w;
        pw  += al * ph * w;
    }
    float sig = 1.f / (1.f + __expf(-pre));
    s_tab[idx] = pre * sig;
    g_tab[idx] = sig * (1.f + pre * (1.f - sig)) * pw;
}

// ---------------- CSR build: per-XCD histograms, L2-local int atomics ----------------

__global__ void count8_kernel(const int* __restrict__ ei,
                              int* __restrict__ cnt_r8, int* __restrict__ cnt_s8) {
    unsigned int xcd = get_xcd();
    int e = blockIdx.x * blockDim.x + threadIdx.x;
    if (e >= N_EDGES) return;
    int send = ei[e], recv = ei[N_EDGES + e];
    __hip_atomic_fetch_add(&cnt_r8[xcd * WPAD + recv], 1,
                           __ATOMIC_RELAXED, __HIP_MEMORY_SCOPE_WORKGROUP);
    __hip_atomic_fetch_add(&cnt_s8[xcd * WPAD + send], 1,
                           __ATOMIC_RELAXED, __HIP_MEMORY_SCOPE_WORKGROUP);
}

__global__ void xcd_prefix_kernel(int* __restrict__ cnt_r8, int* __restrict__ cnt_s8,
                                  int* __restrict__ offs_r, int* __restrict__ offs_s) {
    int a = blockIdx.x * blockDim.x + threadIdx.x;
    if (a >= N_ATOMS) return;
    int t = 0;
    #pragma unroll
    for (int x = 0; x < 8; ++x) {
        int c = cnt_r8[x*WPAD + a];
        cnt_r8[x*WPAD + a] = t;
        t += c;
    }
    offs_r[a] = t;
    t = 0;
    #pragma unroll
    for (int x = 0; x < 8; ++x) {
        int c = cnt_s8[x*WPAD + a];
        cnt_s8[x*WPAD + a] = t;
        t += c;
    }
    offs_s[a] = t;
}

// ---------------- parallel 3-phase exclusive scan over N_ATOMS+1 (both arrays) ----

__global__ void scanA(int* __restrict__ offs_r, int* __restrict__ offs_s,
                      int* __restrict__ bsum) {
    int y = blockIdx.y;
    int* a = y ? offs_s : offs_r;
    const int n = N_ATOMS + 1;
    int i = blockIdx.x * SCAN_B + threadIdx.x;
    int v = (i < n) ? a[i] : 0;
    int lane = threadIdx.x & 63, w = threadIdx.x >> 6;
    int s = v;
    #pragma unroll
    for (int o = 1; o < 64; o <<= 1) {
        int t = __shfl_up(s, o);
        if (lane >= o) s += t;
    }
    __shared__ int wsum[16];
    if (lane == 63) wsum[w] = s;
    __syncthreads();
    if (threadIdx.x < 16) {
        int sc = wsum[threadIdx.x];
        #pragma unroll
        for (int o = 1; o < 16; o <<= 1) {
            int t = __shfl_up(sc, o);
            if ((int)threadIdx.x >= o) sc += t;
        }
        wsum[threadIdx.x] = sc;
    }
    __syncthreads();
    int wpre = (w > 0) ? wsum[w-1] : 0;
    if (i < n) a[i] = s - v + wpre;
    if (threadIdx.x == 0) bsum[y * SCAN_NB + blockIdx.x] = wsum[15];
}

__global__ void scanB(int* __restrict__ bsum) {
    __shared__ int lds[SCAN_NB];
    for (int y = 0; y < 2; ++y) {
        if (threadIdx.x < SCAN_NB) lds[threadIdx.x] = bsum[y*SCAN_NB + threadIdx.x];
        __syncthreads();
        if (threadIdx.x == 0) {
            int run = 0;
            for (int i = 0; i < SCAN_NB; ++i) { int t = lds[i]; lds[i] = run; run += t; }
        }
        __syncthreads();
        if (threadIdx.x < SCAN_NB) bsum[y*SCAN_NB + threadIdx.x] = lds[threadIdx.x];
        __syncthreads();
    }
}

__global__ void scanC(int* __restrict__ offs_r, int* __restrict__ offs_s,
                      const int* __restrict__ bsum) {
    int y = blockIdx.y;
    int* a = y ? offs_s : offs_r;
    int i = blockIdx.x * SCAN_B + threadIdx.x;
    if (i < N_ATOMS + 1) a[i] += bsum[y*SCAN_NB + blockIdx.x];
}

// ---------------- scatter: allocator-style, SINGLE payload ----------------
// pay_r[rs] = (vx,vy,vz, bitcast(send_slot ss))
__global__ void scatter1(const int* __restrict__ ei,
                         const int* __restrict__ offs_r, const int* __restrict__ offs_s,
                         int* __restrict__ cnt_r8, int* __restrict__ cnt_s8,
                         const float* __restrict__ vectors,
                         float4* __restrict__ pay_r) {
    unsigned int xcd = get_xcd();
    int e = blockIdx.x * blockDim.x + threadIdx.x;
    if (e >= N_EDGES) return;
    int send = ei[e], recv = ei[N_EDGES + e];
    int br = __hip_atomic_fetch_add(&cnt_r8[xcd*WPAD + recv], 1,
                                    __ATOMIC_RELAXED, __HIP_MEMORY_SCOPE_WORKGROUP);
    int rs = offs_r[recv] + br;
    int bs = __hip_atomic_fetch_add(&cnt_s8[xcd*WPAD + send], 1,
                                    __ATOMIC_RELAXED, __HIP_MEMORY_SCOPE_WORKGROUP);
    int ss = offs_s[send] + bs;
    float vx = vectors[3*e], vy = vectors[3*e+1], vz = vectors[3*e+2];
    nt_store4(vx, vy, vz, __int_as_float(ss), &pay_r[rs]);
}

// ---------------- fused: fwd + node MLP + bwd; dr2v scattered to send slots ----

__global__ void fused16(const float4* __restrict__ pay_r,
                        const float* __restrict__ positions,
                        const float* __restrict__ lg,
                        const float* __restrict__ W2, const float* __restrict__ w3,
                        const float* __restrict__ field,
                        const int* __restrict__ offs_r,
                        const float* __restrict__ s_tab, const float* __restrict__ g_tab,
                        float4* __restrict__ dr2v_s, float* __restrict__ av6r,
                        float* __restrict__ tepart, float* __restrict__ out) {
    int tid = blockIdx.x * blockDim.x + threadIdx.x;
    int a = tid >> 4;
    int sl = threadIdx.x & 15;
    int lane = threadIdx.x & 63;
    int gb = lane & 48;
    int start = offs_r[a], end = offs_r[a + 1];
    int k0 = start + sl;

    float m[HIDDEN];
    #pragma unroll
    for (int j = 0; j < HIDDEN; ++j) m[j] = 0.f;

    // ---- pass 1: forward via S-table ----
    for (int k = k0; k < end; k += 16) {
        float4 p = pay_r[k];
        float r2 = p.x*p.x + p.y*p.y + p.z*p.z;
        float x = fminf(r2 * TSCALE, (float)(NB - 2) + 0.999f);
        int i = (int)x;
        float f = x - (float)i;
        const float4* r0 = (const float4*)(s_tab + i * HIDDEN);
        const float4* r1 = (const float4*)(s_tab + (i + 1) * HIDDEN);
        #pragma unroll
        for (int q = 0; q < 4; ++q) {
            float4 A = r0[q], B = r1[q];
            m[4*q+0] += A.x + f * (B.x - A.x);
            m[4*q+1] += A.y + f * (B.y - A.y);
            m[4*q+2] += A.z + f * (B.z - A.z);
            m[4*q+3] += A.w + f * (B.w - A.w);
        }
    }

    #pragma unroll
    for (int o = 1; o < 16; o <<= 1) {
        #pragma unroll
        for (int j = 0; j < HIDDEN; ++j) m[j] += __shfl_xor(m[j], o);
    }

    // ---- node MLP, channel j = sl per lane ----
    float aj = 0.f;
    #pragma unroll
    for (int i = 0; i < HIDDEN; ++i) aj += m[i] * W2[i*HIDDEN + sl];
    float sigj = 1.f / (1.f + __expf(-aj));
    float l = lg[a];
    float w3j = w3[sl];
    float sd = aj * sigj * w3j;
    #pragma unroll
    for (int o = 1; o < 16; o <<= 1) sd += __shfl_xor(sd, o);
    float dAj = l * w3j * sigj * (1.f + aj * (1.f - sigj));
    float gown = 0.f;
    #pragma unroll
    for (int q = 0; q < HIDDEN; ++q) {
        float dq = __shfl(dAj, gb | q);
        gown += dq * W2[sl*HIDDEN + q];
    }
    float g[HIDDEN];
    #pragma unroll
    for (int q = 0; q < HIDDEN; ++q) g[q] = __shfl(gown, gb | q);

    float contrib = 0.f;
    if (sl == 0) {
        float ne = sd + positions[3*a]*field[0] + positions[3*a+1]*field[1]
                      + positions[3*a+2]*field[2];
        out[OFF_NE + a] = ne;
        out[OFF_F + 3*a + 0] = -l * field[0];
        out[OFF_F + 3*a + 1] = -l * field[1];
        out[OFF_F + 3*a + 2] = -l * field[2];
        contrib = ne * l;
    }

    // ---- pass 2: backward via G-table; (v,dr2) scattered to send slot ----
    float axx=0.f, axy=0.f, axz=0.f, ayy=0.f, ayz=0.f, azz=0.f;
    for (int k = k0; k < end; k += 16) {
        float4 p = pay_r[k];
        float r2 = p.x*p.x + p.y*p.y + p.z*p.z;
        float x = fminf(r2 * TSCALE, (float)(NB - 2) + 0.999f);
        int i = (int)x;
        float f = x - (float)i;
        const float4* r0 = (const float4*)(g_tab + i * HIDDEN);
        const float4* r1 = (const float4*)(g_tab + (i + 1) * HIDDEN);
        float dr2 = 0.f;
        #pragma unroll
        for (int q = 0; q < 4; ++q) {
            float4 A = r0[q], B = r1[q];
            dr2 -= g[4*q+0] * (A.x + f * (B.x - A.x));
            dr2 -= g[4*q+1] * (A.y + f * (B.y - A.y));
            dr2 -= g[4*q+2] * (A.z + f * (B.z - A.z));
            dr2 -= g[4*q+3] * (A.w + f * (B.w - A.w));
        }
        int ss = __float_as_int(p.w);
        nt_store4(p.x, p.y, p.z, dr2, &dr2v_s[ss]);   // random 16B write
        axx += dr2*p.x*p.x; axy += dr2*p.x*p.y; axz += dr2*p.x*p.z;
        ayy += dr2*p.y*p.y; ayz += dr2*p.y*p.z; azz += dr2*p.z*p.z;
    }
    #pragma unroll
    for (int o = 1; o < 16; o <<= 1) {
        axx += __shfl_xor(axx, o); axy += __shfl_xor(axy, o); axz += __shfl_xor(axz, o);
        ayy += __shfl_xor(ayy, o); ayz += __shfl_xor(ayz, o); azz += __shfl_xor(azz, o);
    }
    if (sl == 0) {
        float2* p = (float2*)(av6r + (size_t)a * 6);
        p[0] = make_float2(axx, axy);
        p[1] = make_float2(axz, ayy);
        p[2] = make_float2(ayz, azz);
    }

    // total-energy block partial (no global atomic)
    __shared__ float red[4];
    if (sl != 0) contrib = 0.f;
    contrib += __shfl_xor(contrib, 16);
    contrib += __shfl_xor(contrib, 32);
    int w = threadIdx.x >> 6;
    if (lane == 0) red[w] = contrib;
    __syncthreads();
    if (threadIdx.x == 0) tepart[blockIdx.x] = red[0]+red[1]+red[2]+red[3];
}

// -------- send-side: fully coalesced single-stream; block virial partials --------

__global__ void bwd_send16(const float4* __restrict__ dr2v_s,
                           const int* __restrict__ offs_s,
                           const float* __restrict__ av6r,
                           float* __restrict__ vpart, float* __restrict__ out) {
    int tid = blockIdx.x * blockDim.x + threadIdx.x;
    int a = tid >> 4;
    int sl = threadIdx.x & 15;
    int start = offs_s[a], end = offs_s[a + 1];
    float axx=0.f, axy=0.f, axz=0.f, ayy=0.f, ayz=0.f, azz=0.f;
    for (int k = start + sl; k < end; k += 16) {
        float4 q = dr2v_s[k];
        float dr2 = q.w;
        axx += dr2*q.x*q.x; axy += dr2*q.x*q.y; axz += dr2*q.x*q.z;
        ayy += dr2*q.y*q.y; ayz += dr2*q.y*q.z; azz += dr2*q.z*q.z;
    }
    #pragma unroll
    for (int o = 1; o < 16; o <<= 1) {
        axx += __shfl_xor(axx, o); axy += __shfl_xor(axy, o); axz += __shfl_xor(axz, o);
        ayy += __shfl_xor(ayy, o); ayz += __shfl_xor(ayz, o); azz += __shfl_xor(azz, o);
    }
    __shared__ float sh6[16][6];
    int grp = threadIdx.x >> 4;
    if (sl == 0) {
        const float2* p = (const float2*)(av6r + (size_t)a * 6);
        float2 p0 = p[0], p1 = p[1], p2 = p[2];
        axx += p0.x; axy += p0.y; axz += p1.x;
        ayy += p1.y; ayz += p2.x; azz += p2.y;
        float* o9 = out + OFF_AV + (size_t)a * 9;
        o9[0] = axx; o9[1] = axy; o9[2] = axz;
        o9[3] = axy; o9[4] = ayy; o9[5] = ayz;
        o9[6] = axz; o9[7] = ayz; o9[8] = azz;
        sh6[grp][0] = axx; sh6[grp][1] = axy; sh6[grp][2] = axz;
        sh6[grp][3] = ayy; sh6[grp][4] = ayz; sh6[grp][5] = azz;
    }
    __syncthreads();
    if (threadIdx.x < 6) {
        float s = 0.f;
        #pragma unroll
        for (int q = 0; q < 16; ++q) s += sh6[q][threadIdx.x];
        vpart[blockIdx.x * 6 + threadIdx.x] = s;
    }
}

// -------- final reduce of TE + virial partials: one block, plain stores --------

__global__ void finalize_kernel(const float* __restrict__ tepart,
                                const float* __restrict__ vpart,
                                float* __restrict__ out) {
    int t = threadIdx.x;
    float acc[7];
    #pragma unroll
    for (int c = 0; c < 7; ++c) acc[c] = 0.f;
    for (int i = t; i < NBLK16; i += 1024) {
        acc[0] += tepart[i];
        const float* p = vpart + (size_t)i * 6;
        acc[1] += p[0]; acc[2] += p[1]; acc[3] += p[2];
        acc[4] += p[3]; acc[5] += p[4]; acc[6] += p[5];
    }
    #pragma unroll
    for (int c = 0; c < 7; ++c) {
        #pragma unroll
        for (int o = 1; o < 64; o <<= 1) acc[c] += __shfl_xor(acc[c], o);
    }
    __shared__ float sh[16][8];
    int lane = t & 63, w = t >> 6;
    if (lane == 0) {
        #pragma unroll
        for (int c = 0; c < 7; ++c) sh[w][c] = acc[c];
    }
    __syncthreads();
    if (t == 0) {
        float s[7];
        #pragma unroll
        for (int c = 0; c < 7; ++c) {
            float v = 0.f;
            #pragma unroll
            for (int q = 0; q < 16; ++q) v += sh[q][c];
            s[c] = v;
        }
        out[OFF_TE] = s[0];
        out[OFF_VIR + 0] = s[1]; out[OFF_VIR + 1] = s[2]; out[OFF_VIR + 2] = s[3];
        out[OFF_VIR + 3] = s[2]; out[OFF_VIR + 4] = s[4]; out[OFF_VIR + 5] = s[5];
        out[OFF_VIR + 6] = s[3]; out[OFF_VIR + 7] = s[5]; out[OFF_VIR + 8] = s[6];
    }
}

// ================= fallback (round-3 verified path) =================

__global__ void count_kernel(const int* __restrict__ ei,
                             int* __restrict__ cnt_r, int* __restrict__ cnt_s,
                             int* __restrict__ rank_r, int* __restrict__ rank_s) {
    int e = blockIdx.x * blockDim.x + threadIdx.x;
    if (e >= N_EDGES) return;
    int send = ei[e], recv = ei[N_EDGES + e];
    rank_r[e] = atomicAdd(&cnt_r[recv], 1);
    rank_s[e] = atomicAdd(&cnt_s[send], 1);
}

__global__ void scan_kernel(int* __restrict__ offs_r, int* __restrict__ offs_s) {
    int* a = (blockIdx.x == 0) ? offs_r : offs_s;
    const int n = N_ATOMS + 1;
    __shared__ int wsum[4];
    __shared__ int carry_s;
    if (threadIdx.x == 0) carry_s = 0;
    __syncthreads();
    int lane = threadIdx.x & 63, w = threadIdx.x >> 6;
    for (int base = 0; base < n; base += 256) {
        int i = base + threadIdx.x;
        int v = (i < n) ? a[i] : 0;
        int s = v;
        #pragma unroll
        for (int o = 1; o < 64; o <<= 1) {
            int t = __shfl_up(s, o);
            if (lane >= o) s += t;
        }
        if (lane == 63) wsum[w] = s;
        __syncthreads();
        int wpre = 0;
        for (int k = 0; k < w; ++k) wpre += wsum[k];
        int incl = s + wpre;
        int total = wsum[0] + wsum[1] + wsum[2] + wsum[3];
        int excl = incl - v + carry_s;
        if (i < n) a[i] = excl;
        __syncthreads();
        if (threadIdx.x == 0) carry_s += total;
        __syncthreads();
    }
}

__global__ void scatter_kernel(const int* __restrict__ ei,
                               const int* __restrict__ offs_r, const int* __restrict__ offs_s,
                               const int* __restrict__ rank_r, const int* __restrict__ rank_s,
                               int* __restrict__ eid_r, int* __restrict__ eid_s) {
    int e = blockIdx.x * blockDim.x + threadIdx.x;
    if (e >= N_EDGES) return;
    int send = ei[e], recv = ei[N_EDGES + e];
    eid_r[offs_r[recv] + rank_r[e]] = e;
    eid_s[offs_s[send] + rank_s[e]] = e;
}

__global__ void fused_kernel(const float* __restrict__ vectors,
                             const float* __restrict__ positions,
                             const float* __restrict__ lg,
                             const float* __restrict__ W1, const float* __restrict__ b1,
                             const float* __restrict__ W2, const float* __restrict__ w3,
                             const float* __restrict__ field, const float* __restrict__ alphas,
                             const int* __restrict__ offs_r, const int* __restrict__ eid_r,
                             float* __restrict__ dr2buf, float* __restrict__ av6,
                             float* __restrict__ out) {
    int a = (blockIdx.x * blockDim.x + threadIdx.x) >> 6;
    int lane = threadIdx.x & 63;
    int start = offs_r[a], end = offs_r[a + 1];
    float al[N_RBF];
    #pragma unroll
    for (int f = 0; f < N_RBF; ++f) al[f] = alphas[f];
    float m[HIDDEN];
    #pragma unroll
    for (int j = 0; j < HIDDEN; ++j) m[j] = 0.f;
    float t[HIDDEN], paw[HIDDEN];
    float vx0 = 0.f, vy0 = 0.f, vz0 = 0.f;
    int e0 = -1;
    int k0 = start + lane;
    for (int k = k0; k < end; k += 64) {
        int e = eid_r[k];
        float vx = vectors[3*e], vy = vectors[3*e+1], vz = vectors[3*e+2];
        float r2 = vx*vx + vy*vy + vz*vz;
        float phi[N_RBF], apf[N_RBF];
        #pragma unroll
        for (int f = 0; f < N_RBF; ++f) { phi[f] = __expf(-r2 * al[f]); apf[f] = al[f] * phi[f]; }
        bool first = (k == k0);
        if (first) { e0 = e; vx0 = vx; vy0 = vy; vz0 = vz; }
        #pragma unroll
        for (int j = 0; j < HIDDEN; ++j) {
            float pre = b1[j];
            float pw = 0.f;
            #pragma unroll
            for (int f = 0; f < N_RBF; ++f) {
                float w = W1[f*HIDDEN + j];
                pre += phi[f] * w;
                pw  += apf[f] * w;
            }
            float sig = 1.f / (1.f + __expf(-pre));
            m[j] += pre * sig;
            if (first) { t[j] = sig * (1.f + pre * (1.f - sig)); paw[j] = pw; }
        }
    }
    #pragma unroll
    for (int o = 1; o < 64; o <<= 1) {
        #pragma unroll
        for (int j = 0; j < HIDDEN; ++j) m[j] += __shfl_xor(m[j], o);
    }
    int jj = lane & 15;
    int gbase = lane & 48;
    float aj = 0.f;
    #pragma unroll
    for (int i = 0; i < HIDDEN; ++i) aj += m[i] * W2[i*HIDDEN + jj];
    float sigj = 1.f / (1.f + __expf(-aj));
    float l = lg[a];
    float sd = aj * sigj * w3[jj];
    #pragma unroll
    for (int o = 1; o < 16; o <<= 1) sd += __shfl_xor(sd, o);
    float dAj = l * w3[jj] * sigj * (1.f + aj * (1.f - sigj));
    float dAv[HIDDEN];
    #pragma unroll
    for (int q = 0; q < HIDDEN; ++q) dAv[q] = __shfl(dAj, gbase | q);
    float gown = 0.f;
    #pragma unroll
    for (int j2 = 0; j2 < HIDDEN; ++j2) gown += dAv[j2] * W2[jj*HIDDEN + j2];
    float g[HIDDEN];
    #pragma unroll
    for (int q = 0; q < HIDDEN; ++q) g[q] = __shfl(gown, gbase | q);
    float contrib = 0.f;
    if (lane == 0) {
        float ne = sd + positions[3*a]*field[0] + positions[3*a+1]*field[1]
                      + positions[3*a+2]*field[2];
        out[OFF_NE + a] = ne;
        out[OFF_F + 3*a + 0] = -l * field[0];
        out[OFF_F + 3*a + 1] = -l * field[1];
        out[OFF_F + 3*a + 2] = -l * field[2];
        contrib = ne * l;
    }
    float axx=0.f, axy=0.f, axz=0.f, ayy=0.f, ayz=0.f, azz=0.f;
    if (k0 < end) {
        float dr2 = 0.f;
        #pragma unroll
        for (int j = 0; j < HIDDEN; ++j) dr2 -= (g[j] * t[j]) * paw[j];
        dr2buf[e0] = dr2;
        axx = dr2*vx0*vx0; axy = dr2*vx0*vy0; axz = dr2*vx0*vz0;
        ayy = dr2*vy0*vy0; ayz = dr2*vy0*vz0; azz = dr2*vz0*vz0;
    }
    for (int k = k0 + 64; k < end; k += 64) {
        int e = eid_r[k];
        float vx = vectors[3*e], vy = vectors[3*e+1], vz = vectors[3*e+2];
        float r2 = vx*vx + vy*vy + vz*vz;
        float phi[N_RBF], apf[N_RBF];
        #pragma unroll
        for (int f = 0; f < N_RBF; ++f) { phi[f] = __expf(-r2 * al[f]); apf[f] = al[f] * phi[f]; }
        float dr2 = 0.f;
        #pragma unroll
        for (int j = 0; j < HIDDEN; ++j) {
            float pre = b1[j];
            float pw = 0.f;
            #pragma unroll
            for (int f = 0; f < N_RBF; ++f) {
                float w = W1[f*HIDDEN + j];
                pre += phi[f] * w;
                pw  += apf[f] * w;
            }
            float sig = 1.f / (1.f + __expf(-pre));
            float tt = sig * (1.f + pre * (1.f - sig));
            dr2 -= (g[j] * tt) * pw;
        }
        dr2buf[e] = dr2;
        axx += dr2*vx*vx; axy += dr2*vx*vy; axz += dr2*vx*vz;
        ayy += dr2*vy*vy; ayz += dr2*vy*vz; azz += dr2*vz*vz;
    }
    #pragma unroll
    for (int o = 1; o < 64; o <<= 1) {
        axx += __shfl_xor(axx, o); axy += __shfl_xor(axy, o); axz += __shfl_xor(axz, o);
        ayy += __shfl_xor(ayy, o); ayz += __shfl_xor(ayz, o); azz += __shfl_xor(azz, o);
    }
    if (lane == 0) {
        float2* p = (float2*)(av6 + (size_t)a * 6);
        p[0] = make_float2(axx, axy);
        p[1] = make_float2(axz, ayy);
        p[2] = make_float2(ayz, azz);
    }
    __shared__ float red[4];
    int w = threadIdx.x >> 6;
    if (lane == 0) red[w] = contrib;
    __syncthreads();
    if (threadIdx.x == 0) atomicAdd(&out[OFF_TE], red[0]+red[1]+red[2]+red[3]);
}

__global__ void bwd_send_kernel(const float* __restrict__ vectors,
                                const int* __restrict__ offs_s, const int* __restrict__ eid_s,
                                const float* __restrict__ dr2buf, const float* __restrict__ av6,
                                float* __restrict__ out) {
    int a = (blockIdx.x * blockDim.x + threadIdx.x) >> 6;
    int lane = threadIdx.x & 63;
    int start = offs_s[a], end = offs_s[a + 1];
    float axx=0.f, axy=0.f, axz=0.f, ayy=0.f, ayz=0.f, azz=0.f;
    for (int k = start + lane; k < end; k += 64) {
        int e = eid_s[k];
        float dr2 = dr2buf[e];
        float vx = vectors[3*e], vy = vectors[3*e+1], vz = vectors[3*e+2];
        axx += dr2*vx*vx; axy += dr2*vx*vy; axz += dr2*vx*vz;
        ayy += dr2*vy*vy; ayz += dr2*vy*vz; azz += dr2*vz*vz;
    }
    #pragma unroll
    for (int o = 1; o < 64; o <<= 1) {
        axx += __shfl_xor(axx, o); axy += __shfl_xor(axy, o); axz += __shfl_xor(axz, o);
        ayy += __shfl_xor(ayy, o); ayz += __shfl_xor(ayz, o); azz += __shfl_xor(azz, o);
    }
    if (lane == 0) {
        const float2* p = (const float2*)(av6 + (size_t)a * 6);
        float2 p0 = p[0], p1 = p[1], p2 = p[2];
        axx += p0.x; axy += p0.y; axz += p1.x;
        ayy += p1.y; ayz += p2.x; azz += p2.y;
        float* o9 = out + OFF_AV + (size_t)a * 9;
        o9[0] = axx; o9[1] = axy; o9[2] = axz;
        o9[3] = axy; o9[4] = ayy; o9[5] = ayz;
        o9[6] = axz; o9[7] = ayz; o9[8] = azz;
    }
}

__global__ void virial_reduce(float* __restrict__ out) {
    const float* av = out + OFF_AV;
    float acc[9];
    #pragma unroll
    for (int c = 0; c < 9; ++c) acc[c] = 0.0f;
    for (int n = blockIdx.x * blockDim.x + threadIdx.x; n < N_ATOMS;
         n += gridDim.x * blockDim.x) {
        #pragma unroll
        for (int c = 0; c < 9; ++c) acc[c] += av[n*9 + c];
    }
    __shared__ float red[4];
    int lane = threadIdx.x & 63, wid = threadIdx.x >> 6;
    #pragma unroll
    for (int c = 0; c < 9; ++c) {
        float v = acc[c];
        #pragma unroll
        for (int o = 32; o > 0; o >>= 1) v += __shfl_down(v, o);
        if (lane == 0) red[wid] = v;
        __syncthreads();
        if (threadIdx.x == 0) atomicAdd(&out[OFF_VIR + c], red[0]+red[1]+red[2]+red[3]);
        __syncthreads();
    }
}

// ---------------- launch ----------------

extern "C" void kernel_launch(void* const* d_in, const int* in_sizes, int n_in,
                              void* d_out, int out_size, void* d_ws, size_t ws_size,
                              hipStream_t stream) {
    const float* positions = (const float*)d_in[0];
    const float* vectors   = (const float*)d_in[1];
    const float* lg        = (const float*)d_in[2];
    const float* W1        = (const float*)d_in[3];
    const float* b1        = (const float*)d_in[4];
    const float* W2        = (const float*)d_in[5];
    const float* w3        = (const float*)d_in[6];
    const float* field     = (const float*)d_in[7];
    const float* alphas    = (const float*)d_in[8];
    const int*   edge_index= (const int*)  d_in[9];
    float* out = (float*)d_out;
    int*   wsi = (int*)d_ws;
    float* wsf = (float*)d_ws;

    dim3 blk(256);
    dim3 egrid((N_EDGES + 255) / 256);     // 12500
    dim3 g16(NBLK16);                      // 6250 blocks, 16 lanes/atom

    if (ws_size >= (size_t)NEND * 4) {
        float*  s_tab  = wsf + NTAB_S;
        float*  g_tab  = wsf + NTAB_G;
        int*    offs_r = wsi + NOFF_R;
        int*    offs_s = wsi + NOFF_S;
        int*    cnt_r8 = wsi + NCNT_R8;
        int*    cnt_s8 = wsi + NCNT_S8;
        float*  tepart = wsf + NTEP;
        float*  vpart  = wsf + NVPART;
        float*  av6r   = wsf + NAV6R;
        float4* pay_r  = (float4*)(wsf + NPAY_R);
        float4* dr2v_s = (float4*)(wsf + NDR2V);
        int*    bsum   = wsi + NBSUM;      // aliases pay_r head (dead before scatter)

        // offs_r, offs_s, cnt_r8, cnt_s8 contiguous: one memset
        hipMemsetAsync(offs_r, 0, (size_t)18 * WPAD * sizeof(int), stream);

        build_tables<<<dim3(NB*HIDDEN/256), blk, 0, stream>>>(W1, b1, alphas, s_tab, g_tab);
        count8_kernel<<<egrid, blk, 0, stream>>>(edge_index, cnt_r8, cnt_s8);
        xcd_prefix_kernel<<<dim3((N_ATOMS+255)/256), blk, 0, stream>>>(cnt_r8, cnt_s8,
                                                                       offs_r, offs_s);
        scanA<<<dim3(SCAN_NB, 2), dim3(SCAN_B), 0, stream>>>(offs_r, offs_s, bsum);
        scanB<<<dim3(1), dim3(256), 0, stream>>>(bsum);
        scanC<<<dim3(SCAN_NB, 2), dim3(SCAN_B), 0, stream>>>(offs_r, offs_s, bsum);
        scatter1<<<egrid, blk, 0, stream>>>(edge_index, offs_r, offs_s,
                                            cnt_r8, cnt_s8, vectors, pay_r);
        fused16<<<g16, blk, 0, stream>>>(pay_r, positions, lg, W2, w3, field,
                                         offs_r, s_tab, g_tab, dr2v_s, av6r, tepart, out);
        bwd_send16<<<g16, blk, 0, stream>>>(dr2v_s, offs_s, av6r, vpart, out);
        finalize_kernel<<<dim3(1), dim3(1024), 0, stream>>>(tepart, vpart, out);
    } else {
        // fallback: round-3 verified path (67.2 MB ws)
        int*   offs_r = wsi + WOFF_OFFS_R;
        int*   offs_s = wsi + WOFF_OFFS_S;
        int*   rank_r = wsi + WOFF_RANK_R;
        int*   rank_s = wsi + WOFF_RANK_S;
        int*   eid_r  = wsi + WOFF_EID_R;
        int*   eid_s  = wsi + WOFF_EID_S;
        float* dr2buf = wsf + WOFF_DR2;
        float* av6    = wsf + WOFF_AV6;
        dim3 agrid(N_ATOMS / 4);

        hipMemsetAsync(offs_r, 0, (size_t)2 * WPAD * sizeof(int), stream);
        hipMemsetAsync(out + OFF_TE, 0, sizeof(float), stream);
        hipMemsetAsync(out + OFF_VIR, 0, 9 * sizeof(float), stream);

        count_kernel<<<egrid, blk, 0, stream>>>(edge_index, offs_r, offs_s, rank_r, rank_s);
        scan_kernel<<<dim3(2), blk, 0, stream>>>(offs_r, offs_s);
        scatter_kernel<<<egrid, blk, 0, stream>>>(edge_index, offs_r, offs_s,
                                                  rank_r, rank_s, eid_r, eid_s);
        fused_kernel<<<agrid, blk, 0, stream>>>(vectors, positions, lg, W1, b1, W2, w3,
                                                field, alphas, offs_r, eid_r, dr2buf, av6, out);
        bwd_send_kernel<<<agrid, blk, 0, stream>>>(vectors, offs_s, eid_s, dr2buf, av6, out);
        virial_reduce<<<dim3(256), blk, 0, stream>>>(out);
    }
}